// Round 2
// baseline (3367.662 us; speedup 1.0000x reference)
//
#include <hip/hip_runtime.h>
#include <hip/hip_bf16.h>

#define B 16
#define V 1024
#define D 16
#define E 64
#define F 16
#define H 128
#define HD 64
#define BV (B*V)      // 16384
#define BVD (B*V*D)   // 262144

// ---- workspace layout (float offsets) ----
#define OFF_NODE_ENC 0
#define OFF_H        (OFF_NODE_ENC + BV*H)     // h edge states (B,V,D,H)
#define OFF_NMSG     (OFF_H + BVD*H)
#define OFF_EMB      (OFF_NMSG + BV*H)
#define OFF_NW       (OFF_EMB + V*E)
#define OFF_DATTN    (OFF_NW + BVD)
#define OFF_NORM     (OFF_DATTN + BVD)
#define OFF_FLOWA    (OFF_NORM + BVD)
#define OFF_FLOWB    (OFF_FLOWA + BVD)
#define OFF_DV       (OFF_FLOWB + BVD)
#define OFF_ACC      (OFF_DV + BV)             // [0:16) flow_cost, [16:32) dual, [32:48) dual_demand
#define ZERO_START   OFF_FLOWA
#define ZERO_COUNT   (2*BVD + BV + 64)

__global__ __launch_bounds__(256) void k_zero(float* ws){
  int i = blockIdx.x*256 + threadIdx.x;
  if (i < ZERO_COUNT) ws[ZERO_START + i] = 0.f;
}

// embedding max_norm=1 normalization: (V,E) -> f32
__global__ __launch_bounds__(64) void k_embnorm(const float* __restrict__ emb, float* __restrict__ embn){
  int v = blockIdx.x, e = threadIdx.x;
  float val = emb[v*E + e];
  float ss = val*val;
  #pragma unroll
  for (int off=32; off>0; off>>=1) ss += __shfl_down(ss, off);
  ss = __shfl(ss, 0);
  float scale = 1.f / fmaxf(sqrtf(ss), 1.f);
  embn[v*E + e] = val * scale;
}

// node_enc = [emb_n | node_features] @ W_enc + b_enc   (M=BV, K=80, N=128)
__global__ __launch_bounds__(256) void k_enc(const float* __restrict__ embn, const float* __restrict__ nf,
                                             const float* __restrict__ Wenc, const float* __restrict__ benc,
                                             float* __restrict__ ne){
  __shared__ float As[16][80];
  int tid = threadIdx.x;
  int m0 = blockIdx.x*16;
  for (int idx=tid; idx<16*80; idx+=256){
    int i = idx/80, k = idx%80;
    int m = m0 + i; int v = m & (V-1);
    As[i][k] = (k < E) ? embn[v*E + k] : nf[m*F + (k-E)];
  }
  __syncthreads();
  int c = tid & 127, half = tid >> 7;
  float acc[8] = {0,0,0,0,0,0,0,0};
  for (int kk=0; kk<80; kk+=4){
    float w[4];
    #pragma unroll
    for (int u=0;u<4;u++) w[u] = Wenc[(kk+u)*H + c];
    #pragma unroll
    for (int i=0;i<8;i++){
      const float4 av = *reinterpret_cast<const float4*>(&As[half*8+i][kk]);
      acc[i] += av.x*w[0] + av.y*w[1] + av.z*w[2] + av.w*w[3];
    }
  }
  float bb = benc[c];
  #pragma unroll
  for (int i=0;i<8;i++){
    int m = m0 + half*8 + i;
    ne[m*H + c] = acc[i] + bb;
  }
}

// h init = gather(node_enc, adj)  (float4 copies)
__global__ __launch_bounds__(256) void k_hinit(const float* __restrict__ ne, const int* __restrict__ adj,
                                               float* __restrict__ h){
  int node = blockIdx.x; int b = node >> 10;
  for (int idx=threadIdx.x; idx<D*H/4; idx+=256){
    int d = idx >> 5, j4 = idx & 31;     // 32 float4 per row of 128
    int a = adj[node*D + d];
    const float4 v = reinterpret_cast<const float4*>(&ne[(b*V + a)*H])[j4];
    reinterpret_cast<float4*>(&h[(node*D + d)*H])[j4] = v;
  }
}

// Fused DirectionalGAT per node: t=tanh(h@Wg+bg); logits=t.a; attn=softmax; node_msg=sum attn*t
__global__ __launch_bounds__(64) void k_gat(const float* __restrict__ h, const float* __restrict__ Wg,
                                            const float* __restrict__ bg, const float* __restrict__ ag,
                                            float* __restrict__ nmsg){
  __shared__ float hs[16][128];
  __shared__ float ts[16][132];
  __shared__ float lg[16], at_s[16];
  int tid = threadIdx.x;
  int node = blockIdx.x;
  for (int idx=tid; idx<D*H/4; idx+=64){
    int i = idx >> 5, j4 = idx & 31;
    reinterpret_cast<float4*>(&hs[i][0])[j4] =
        reinterpret_cast<const float4*>(&h[(node*D + i)*H])[j4];
  }
  __syncthreads();
  int c0 = tid, c1 = tid + 64;
  float acc0[16], acc1[16];
  #pragma unroll
  for (int i=0;i<16;i++){ acc0[i]=0.f; acc1[i]=0.f; }
  for (int kk=0; kk<H; kk+=4){
    float w0[4], w1[4];
    #pragma unroll
    for (int u=0;u<4;u++){ w0[u]=Wg[(kk+u)*H + c0]; w1[u]=Wg[(kk+u)*H + c1]; }
    #pragma unroll
    for (int i=0;i<16;i++){
      const float4 hv = *reinterpret_cast<const float4*>(&hs[i][kk]);
      acc0[i] += hv.x*w0[0] + hv.y*w0[1] + hv.z*w0[2] + hv.w*w0[3];
      acc1[i] += hv.x*w1[0] + hv.y*w1[1] + hv.z*w1[2] + hv.w*w1[3];
    }
  }
  float b0 = bg[c0], b1 = bg[c1];
  #pragma unroll
  for (int i=0;i<16;i++){
    ts[i][c0] = tanhf(acc0[i] + b0);
    ts[i][c1] = tanhf(acc1[i] + b1);
  }
  __syncthreads();
  if (tid < 16){
    float s = 0.f;
    for (int c=0;c<H;c++) s += ts[tid][c] * ag[c];
    lg[tid] = s;
  }
  __syncthreads();
  if (tid < 16){
    float m = lg[0];
    #pragma unroll
    for (int j=1;j<16;j++) m = fmaxf(m, lg[j]);
    at_s[tid] = expf(lg[tid] - m);
  }
  __syncthreads();
  float asum = 0.f;
  #pragma unroll
  for (int j=0;j<16;j++) asum += at_s[j];
  float inv = 1.f/asum;
  float nm0=0.f, nm1=0.f;
  #pragma unroll
  for (int d=0; d<16; d++){
    float a = at_s[d]*inv;
    nm0 += a * ts[d][c0];
    nm1 += a * ts[d][c1];
  }
  nmsg[node*H + c0] = nm0;
  nmsg[node*H + c1] = nm1;
}

// Fused GRU per half-node (8 edge rows): x=tanh(gather(nmsg+ne)); gx=x@Wx+b; gh=h@Wh; GRU update in place
__global__ __launch_bounds__(128) void k_gru(const float* __restrict__ ne, const float* __restrict__ nmsg,
    const int* __restrict__ adj, const float* __restrict__ Wx, const float* __restrict__ Wh,
    const float* __restrict__ bgru, float* __restrict__ h){
  __shared__ float xs[8][128], hs[8][128];
  __shared__ float sA[8][256], sCx[8][128], sCh[8][128];
  int tid = threadIdx.x;
  int blk = blockIdx.x;
  int node = blk >> 1, half = blk & 1;
  int b = node >> 10;
  int dbase = half*8;
  for (int idx=tid; idx<8*128; idx+=128){
    int i = idx >> 7, j = idx & 127;
    int d = dbase + i;
    int a = adj[node*D + d];
    int base = (b*V + a)*H + j;
    xs[i][j] = tanhf(nmsg[base] + ne[base]);
    hs[i][j] = h[(node*D + d)*H + j];
  }
  __syncthreads();
  int c0 = tid, c1 = tid+128, c2 = tid+256;
  float ax0[8],ax1[8],ax2[8],ah0[8],ah1[8],ah2[8];
  #pragma unroll
  for (int i=0;i<8;i++){ ax0[i]=ax1[i]=ax2[i]=0.f; ah0[i]=ah1[i]=ah2[i]=0.f; }
  for (int kk=0; kk<H; kk+=4){
    float wx0[4],wx1[4],wx2[4],wh0[4],wh1[4],wh2[4];
    #pragma unroll
    for (int u=0;u<4;u++){
      int r = (kk+u)*384;
      wx0[u]=Wx[r+c0]; wx1[u]=Wx[r+c1]; wx2[u]=Wx[r+c2];
      wh0[u]=Wh[r+c0]; wh1[u]=Wh[r+c1]; wh2[u]=Wh[r+c2];
    }
    #pragma unroll
    for (int i=0;i<8;i++){
      const float4 xv = *reinterpret_cast<const float4*>(&xs[i][kk]);
      const float4 hv = *reinterpret_cast<const float4*>(&hs[i][kk]);
      ax0[i] += xv.x*wx0[0]+xv.y*wx0[1]+xv.z*wx0[2]+xv.w*wx0[3];
      ax1[i] += xv.x*wx1[0]+xv.y*wx1[1]+xv.z*wx1[2]+xv.w*wx1[3];
      ax2[i] += xv.x*wx2[0]+xv.y*wx2[1]+xv.z*wx2[2]+xv.w*wx2[3];
      ah0[i] += hv.x*wh0[0]+hv.y*wh0[1]+hv.z*wh0[2]+hv.w*wh0[3];
      ah1[i] += hv.x*wh1[0]+hv.y*wh1[1]+hv.z*wh1[2]+hv.w*wh1[3];
      ah2[i] += hv.x*wh2[0]+hv.y*wh2[1]+hv.z*wh2[2]+hv.w*wh2[3];
    }
  }
  float bg0 = bgru[c0], bg1 = bgru[c1], bg2 = bgru[c2];
  #pragma unroll
  for (int i=0;i<8;i++){
    sA[i][tid]     = ax0[i] + ah0[i] + bg0;
    sA[i][tid+128] = ax1[i] + ah1[i] + bg1;
    sCx[i][tid]    = ax2[i] + bg2;
    sCh[i][tid]    = ah2[i];
  }
  __syncthreads();
  int j = tid;
  #pragma unroll
  for (int i=0;i<8;i++){
    float z = 1.f/(1.f+expf(-sA[i][j]));
    float r = 1.f/(1.f+expf(-sA[i][j+128]));
    float cand = tanhf(sCx[i][j] + r*sCh[i][j]);
    float hn = z*hs[i][j] + (1.f-z)*cand;
    h[(node*D + dbase + i)*H + j] = hn;
  }
}

// Decoder per half-node: dec_in=[h | h + h_opp]; nw = tanh(dec_in@W1+b1)@W2+b2
__global__ __launch_bounds__(64) void k_dec(const float* __restrict__ h, const int* __restrict__ adj,
    const float* __restrict__ W1, const float* __restrict__ b1, const float* __restrict__ W2,
    const float* __restrict__ b2_, float* __restrict__ nw){
  __shared__ float din[8][256];
  int tid = threadIdx.x;
  int blk = blockIdx.x;
  int node = blk >> 1, half = blk & 1, b = node >> 10;
  int dbase = half*8;
  for (int idx=tid; idx<8*256; idx+=64){
    int i = idx >> 8, q = idx & 255;
    int d = dbase + i;
    float hv = h[(node*D + d)*H + (q & 127)];
    if (q < 128){
      din[i][q] = hv;
    } else {
      int a = adj[node*D + d];
      int od = d ^ 1;
      din[i][q] = hv + h[((b*V + a)*D + od)*H + (q-128)];
    }
  }
  __syncthreads();
  int c = tid;
  float acc[8] = {0,0,0,0,0,0,0,0};
  for (int kk=0; kk<256; kk+=4){
    float w[4];
    #pragma unroll
    for (int u=0;u<4;u++) w[u] = W1[(kk+u)*HD + c];
    #pragma unroll
    for (int i=0;i<8;i++){
      const float4 v = *reinterpret_cast<const float4*>(&din[i][kk]);
      acc[i] += v.x*w[0]+v.y*w[1]+v.z*w[2]+v.w*w[3];
    }
  }
  float bd = b1[c];
  float w2 = W2[c];
  float b2v = b2_[0];
  #pragma unroll
  for (int i=0;i<8;i++){
    float t = tanhf(acc[i] + bd) * w2;
    #pragma unroll
    for (int off=32; off>0; off>>=1) t += __shfl_down(t, off);
    if (tid == 0) nw[node*D + dbase + i] = t + b2v;
  }
}

// dest_attn = softmax_d( nw[b, inv_adj[v,d], d] )
__global__ __launch_bounds__(256) void k_dattn(const float* __restrict__ nw, const int* __restrict__ invadj,
                                               float* __restrict__ dattn){
  int node = blockIdx.x*256 + threadIdx.x;
  if (node >= BV) return;
  int b = node >> 10;
  float vals[16];
  #pragma unroll
  for (int d=0; d<16; d++){
    int ia = invadj[node*D + d];
    vals[d] = nw[(b*V + ia)*D + d];
  }
  float m = vals[0];
  #pragma unroll
  for (int d=1; d<16; d++) m = fmaxf(m, vals[d]);
  float s = 0.f;
  #pragma unroll
  for (int d=0; d<16; d++){ vals[d] = expf(vals[d]-m); s += vals[d]; }
  float inv = 1.f/s;
  #pragma unroll
  for (int d=0; d<16; d++) dattn[node*D + d] = vals[d]*inv;
}

// normalized = sparsemax_d( dattn[b, adj[v,d], d] )
__global__ __launch_bounds__(256) void k_sparse(const float* __restrict__ dattn, const int* __restrict__ adj,
                                                float* __restrict__ norm_){
  int node = blockIdx.x*256 + threadIdx.x;
  if (node >= BV) return;
  int b = node >> 10;
  float z[16], s[16];
  #pragma unroll
  for (int d=0; d<16; d++){
    int a = adj[node*D + d];
    z[d] = dattn[(b*V + a)*D + d];
    s[d] = z[d];
  }
  // bitonic sort ascending (fully unrolled, registers only)
  #pragma unroll
  for (int k2 = 2; k2 <= 16; k2 <<= 1){
    #pragma unroll
    for (int jj = k2 >> 1; jj > 0; jj >>= 1){
      #pragma unroll
      for (int i = 0; i < 16; i++){
        int l = i ^ jj;
        if (l > i){
          bool up = ((i & k2) == 0);
          float a = s[i], bb = s[l];
          bool sw = up ? (a > bb) : (a < bb);
          if (sw){ s[i]=bb; s[l]=a; }
        }
      }
    }
  }
  float cs = 0.f, zcs = 0.f; int kz = 1;
  #pragma unroll
  for (int j=0;j<16;j++){
    float zj = s[15-j];   // descending
    cs += zj;
    if (1.f + (float)(j+1)*zj > cs){ kz = j+1; zcs = cs; }
  }
  float tau = (zcs - 1.f)/(float)kz;
  #pragma unroll
  for (int d=0; d<16; d++) norm_[node*D + d] = fmaxf(z[d]-tau, 0.f);
}

// one MCF iteration
__global__ __launch_bounds__(256) void k_flow(const float* __restrict__ fprev, const float* __restrict__ norm_,
    const float* __restrict__ dem, const int* __restrict__ invadj, float* __restrict__ fnext){
  int node = blockIdx.x*256 + threadIdx.x;
  if (node >= BV) return;
  int b = node >> 10;
  float inflow = 0.f;
  #pragma unroll
  for (int d=0; d<16; d++){
    int ia = invadj[node*D + d];
    inflow += fprev[(b*V + ia)*D + d];
  }
  float s = fmaxf(inflow - dem[node], 0.f);
  #pragma unroll
  for (int d=0; d<16; d++) fnext[node*D + d] = norm_[node*D + d]*s;
}

// dual_vars per node + dual_demand accumulation
__global__ __launch_bounds__(128) void k_dualvars(const float* __restrict__ h, const float* __restrict__ W1,
    const float* __restrict__ b1, const float* __restrict__ W2, const float* __restrict__ b2_,
    const float* __restrict__ dem, float* __restrict__ dv, float* __restrict__ accdd){
  __shared__ float ns[128];
  int node = blockIdx.x; int b = node >> 10;
  int tid = threadIdx.x;
  float s = 0.f;
  #pragma unroll
  for (int d=0; d<16; d++) s += h[(node*D + d)*H + tid];
  ns[tid] = s;
  __syncthreads();
  if (tid < 64){
    float acc = 0.f;
    for (int k=0;k<128;k++) acc += ns[k]*W1[k*HD + tid];
    float t = tanhf(acc + b1[tid]) * W2[tid];
    #pragma unroll
    for (int off=32; off>0; off>>=1) t += __shfl_down(t, off);
    if (tid == 0){
      float val = fmaxf(t + b2_[0], 0.f);
      dv[node] = val;
      atomicAdd(&accdd[b], val * dem[node]);
    }
  }
}

// flow cost + dual flow iterations + dual cost (fused, one thread per edge)
__global__ __launch_bounds__(256) void k_cost(const float* __restrict__ flow, const float* __restrict__ dv,
    const int* __restrict__ adj, float* __restrict__ accF, float* __restrict__ accD){
  int gid = blockIdx.x*256 + threadIdx.x;
  int b = gid >> 14;          // V*D = 16384
  int a = adj[gid];
  float diff = dv[b*V + a];   // dual == 0 (mask==0)
  float f = 0.f, vel = 0.f;
  #pragma unroll
  for (int it=0; it<10; it++){
    float g = 2.f*f + diff;
    vel = 0.9f*vel - 0.01f*g;
    f = fmaxf(f + vel, 0.f);
  }
  float cd = f*f + diff*f;
  float fl = flow[gid];
  float cf = fl*fl;
  #pragma unroll
  for (int off=32; off>0; off>>=1){ cd += __shfl_down(cd, off); cf += __shfl_down(cf, off); }
  __shared__ float r1[4], r2[4];
  int lane = threadIdx.x & 63, w = threadIdx.x >> 6;
  if (lane==0){ r1[w]=cf; r2[w]=cd; }
  __syncthreads();
  if (threadIdx.x==0){
    atomicAdd(&accF[b], r1[0]+r1[1]+r1[2]+r1[3]);
    atomicAdd(&accD[b], r2[0]+r2[1]+r2[2]+r2[3]);
  }
}

__global__ __launch_bounds__(64) void k_final(const float* __restrict__ acc, float* __restrict__ out){
  int b = threadIdx.x;
  if (b < B){
    float fc = acc[b], dc = acc[16+b], dd = acc[32+b];
    out[b] = fc - (dc - dd);
  }
}

extern "C" void kernel_launch(void* const* d_in, const int* in_sizes, int n_in,
                              void* d_out, int out_size, void* d_ws, size_t ws_size,
                              hipStream_t stream){
  (void)in_sizes; (void)n_in; (void)out_size; (void)ws_size;
  const float* demands = (const float*)d_in[0];
  const float* nf      = (const float*)d_in[1];
  const float* emb     = (const float*)d_in[4];
  const float* Wenc    = (const float*)d_in[5];
  const float* benc    = (const float*)d_in[6];
  const float* Wgat    = (const float*)d_in[7];
  const float* bgat    = (const float*)d_in[8];
  const float* agat    = (const float*)d_in[9];
  const float* Wgx     = (const float*)d_in[10];
  const float* Wgh     = (const float*)d_in[11];
  const float* bgru    = (const float*)d_in[12];
  const float* Wd1     = (const float*)d_in[13];
  const float* bd1     = (const float*)d_in[14];
  const float* Wd2     = (const float*)d_in[15];
  const float* bd2     = (const float*)d_in[16];
  const float* Wu1     = (const float*)d_in[17];
  const float* bu1     = (const float*)d_in[18];
  const float* Wu2     = (const float*)d_in[19];
  const float* bu2     = (const float*)d_in[20];
  const int* adj       = (const int*)d_in[21];
  const int* invadj    = (const int*)d_in[22];

  float* ws    = (float*)d_ws;
  float* ne    = ws + OFF_NODE_ENC;
  float* h     = ws + OFF_H;
  float* nmsg  = ws + OFF_NMSG;
  float* embn  = ws + OFF_EMB;
  float* nw    = ws + OFF_NW;
  float* dattn = ws + OFF_DATTN;
  float* nrm   = ws + OFF_NORM;
  float* fa    = ws + OFF_FLOWA;
  float* fb    = ws + OFF_FLOWB;
  float* dv    = ws + OFF_DV;
  float* acc   = ws + OFF_ACC;

  k_zero<<<(ZERO_COUNT+255)/256, 256, 0, stream>>>(ws);
  k_embnorm<<<V, 64, 0, stream>>>(emb, embn);
  k_enc<<<BV/16, 256, 0, stream>>>(embn, nf, Wenc, benc, ne);
  k_hinit<<<BV, 256, 0, stream>>>(ne, adj, h);
  for (int layer=0; layer<2; layer++){
    k_gat<<<BV, 64, 0, stream>>>(h, Wgat, bgat, agat, nmsg);
    k_gru<<<BV*2, 128, 0, stream>>>(ne, nmsg, adj, Wgx, Wgh, bgru, h);
  }
  k_dec<<<BV*2, 64, 0, stream>>>(h, adj, Wd1, bd1, Wd2, bd2, nw);
  k_dattn<<<BV/256, 256, 0, stream>>>(nw, invadj, dattn);
  k_sparse<<<BV/256, 256, 0, stream>>>(dattn, adj, nrm);
  float* src = fa; float* dst = fb;
  for (int it=0; it<10; it++){
    k_flow<<<BV/256, 256, 0, stream>>>(src, nrm, demands, invadj, dst);
    float* t = dst; dst = src; src = t;
  }
  // after even # of iters, final flow is back in fa (== src)
  k_dualvars<<<BV, 128, 0, stream>>>(h, Wu1, bu1, Wu2, bu2, demands, dv, acc+32);
  k_cost<<<BVD/256, 256, 0, stream>>>(src, dv, adj, acc, acc+16);
  k_final<<<1, 64, 0, stream>>>(acc, (float*)d_out);
}

// Round 3
// 1580.255 us; speedup vs baseline: 2.1311x; 2.1311x over previous
//
#include <hip/hip_runtime.h>
#include <hip/hip_bf16.h>

#define B 16
#define V 1024
#define D 16
#define E 64
#define F 16
#define H 128
#define HD 64
#define BV (B*V)      // 16384
#define BVD (B*V*D)   // 262144

// ---- workspace layout (float offsets) ----
#define OFF_NODE_ENC 0
#define OFF_H        (OFF_NODE_ENC + BV*H)     // h edge states (B,V,D,H)
#define OFF_NMSG     (OFF_H + BVD*H)
#define OFF_EMB      (OFF_NMSG + BV*H)
#define OFF_NW       (OFF_EMB + V*E)
#define OFF_DATTN    (OFF_NW + BVD)
#define OFF_NORM     (OFF_DATTN + BVD)
#define OFF_FLOWA    (OFF_NORM + BVD)
#define OFF_FLOWB    (OFF_FLOWA + BVD)
#define OFF_DV       (OFF_FLOWB + BVD)
#define OFF_ACC      (OFF_DV + BV)             // [0:16) flow_cost, [16:32) dual, [32:48) dual_demand
#define OFF_WT       (OFF_ACC + 64)            // 512x256 bf16 packed GRU weights = 65536 floats
#define ZERO_START   OFF_FLOWA
#define ZERO_COUNT   (2*BVD + BV + 64)

typedef __attribute__((ext_vector_type(8))) short bf16x8;
typedef __attribute__((ext_vector_type(4))) float f32x4;

__device__ __forceinline__ short f2bf(float f){
  __hip_bfloat16 b = __float2bfloat16(f);
  return *reinterpret_cast<short*>(&b);
}

__global__ __launch_bounds__(256) void k_zero(float* ws){
  int i = blockIdx.x*256 + threadIdx.x;
  if (i < ZERO_COUNT) ws[ZERO_START + i] = 0.f;
}

// embedding max_norm=1 normalization: (V,E) -> f32
__global__ __launch_bounds__(64) void k_embnorm(const float* __restrict__ emb, float* __restrict__ embn){
  int v = blockIdx.x, e = threadIdx.x;
  float val = emb[v*E + e];
  float ss = val*val;
  #pragma unroll
  for (int off=32; off>0; off>>=1) ss += __shfl_down(ss, off);
  ss = __shfl(ss, 0);
  float scale = 1.f / fmaxf(sqrtf(ss), 1.f);
  embn[v*E + e] = val * scale;
}

// node_enc = [emb_n | node_features] @ W_enc + b_enc   (M=BV, K=80, N=128)
__global__ __launch_bounds__(256) void k_enc(const float* __restrict__ embn, const float* __restrict__ nf,
                                             const float* __restrict__ Wenc, const float* __restrict__ benc,
                                             float* __restrict__ ne){
  __shared__ float As[16][80];
  int tid = threadIdx.x;
  int m0 = blockIdx.x*16;
  for (int idx=tid; idx<16*80; idx+=256){
    int i = idx/80, k = idx%80;
    int m = m0 + i; int v = m & (V-1);
    As[i][k] = (k < E) ? embn[v*E + k] : nf[m*F + (k-E)];
  }
  __syncthreads();
  int c = tid & 127, half = tid >> 7;
  float acc[8] = {0,0,0,0,0,0,0,0};
  for (int kk=0; kk<80; kk+=4){
    float w[4];
    #pragma unroll
    for (int u=0;u<4;u++) w[u] = Wenc[(kk+u)*H + c];
    #pragma unroll
    for (int i=0;i<8;i++){
      const float4 av = *reinterpret_cast<const float4*>(&As[half*8+i][kk]);
      acc[i] += av.x*w[0] + av.y*w[1] + av.z*w[2] + av.w*w[3];
    }
  }
  float bb = benc[c];
  #pragma unroll
  for (int i=0;i<8;i++){
    int m = m0 + half*8 + i;
    ne[m*H + c] = acc[i] + bb;
  }
}

// h init = gather(node_enc, adj)  (float4 copies)
__global__ __launch_bounds__(256) void k_hinit(const float* __restrict__ ne, const int* __restrict__ adj,
                                               float* __restrict__ h){
  int node = blockIdx.x; int b = node >> 10;
  for (int idx=threadIdx.x; idx<D*H/4; idx+=256){
    int d = idx >> 5, j4 = idx & 31;     // 32 float4 per row of 128
    int a = adj[node*D + d];
    const float4 v = reinterpret_cast<const float4*>(&ne[(b*V + a)*H])[j4];
    reinterpret_cast<float4*>(&h[(node*D + d)*H])[j4] = v;
  }
}

// Fused DirectionalGAT per node: t=tanh(h@Wg+bg); logits=t.a; attn=softmax; node_msg=sum attn*t
__global__ __launch_bounds__(64) void k_gat(const float* __restrict__ h, const float* __restrict__ Wg,
                                            const float* __restrict__ bg, const float* __restrict__ ag,
                                            float* __restrict__ nmsg){
  __shared__ float hs[16][128];
  __shared__ float ts[16][132];
  __shared__ float lg[16], at_s[16];
  int tid = threadIdx.x;
  int node = blockIdx.x;
  for (int idx=tid; idx<D*H/4; idx+=64){
    int i = idx >> 5, j4 = idx & 31;
    reinterpret_cast<float4*>(&hs[i][0])[j4] =
        reinterpret_cast<const float4*>(&h[(node*D + i)*H])[j4];
  }
  __syncthreads();
  int c0 = tid, c1 = tid + 64;
  float acc0[16], acc1[16];
  #pragma unroll
  for (int i=0;i<16;i++){ acc0[i]=0.f; acc1[i]=0.f; }
  for (int kk=0; kk<H; kk+=4){
    float w0[4], w1[4];
    #pragma unroll
    for (int u=0;u<4;u++){ w0[u]=Wg[(kk+u)*H + c0]; w1[u]=Wg[(kk+u)*H + c1]; }
    #pragma unroll
    for (int i=0;i<16;i++){
      const float4 hv = *reinterpret_cast<const float4*>(&hs[i][kk]);
      acc0[i] += hv.x*w0[0] + hv.y*w0[1] + hv.z*w0[2] + hv.w*w0[3];
      acc1[i] += hv.x*w1[0] + hv.y*w1[1] + hv.z*w1[2] + hv.w*w1[3];
    }
  }
  float b0 = bg[c0], b1 = bg[c1];
  #pragma unroll
  for (int i=0;i<16;i++){
    ts[i][c0] = tanhf(acc0[i] + b0);
    ts[i][c1] = tanhf(acc1[i] + b1);
  }
  __syncthreads();
  // logits: parallel over 64 threads: d = tid>>2, quarter q = tid&3
  {
    int d = tid >> 2, q = tid & 3;
    float p = 0.f;
    for (int c=q*32; c<q*32+32; c++) p += ts[d][c]*ag[c];
    p += __shfl_down(p, 2);
    p += __shfl_down(p, 1);
    if (q == 0) lg[d] = p;
  }
  __syncthreads();
  if (tid < 16){
    float m = lg[0];
    #pragma unroll
    for (int j=1;j<16;j++) m = fmaxf(m, lg[j]);
    at_s[tid] = expf(lg[tid] - m);
  }
  __syncthreads();
  float asum = 0.f;
  #pragma unroll
  for (int j=0;j<16;j++) asum += at_s[j];
  float inv = 1.f/asum;
  float nm0=0.f, nm1=0.f;
  #pragma unroll
  for (int d=0; d<16; d++){
    float a = at_s[d]*inv;
    nm0 += a * ts[d][c0];
    nm1 += a * ts[d][c1];
  }
  nmsg[node*H + c0] = nm0;
  nmsg[node*H + c1] = nm1;
}

// pack GRU weights as bf16, n-major: Wt[n][k], n in [0,512): groups z,r,cx,ch; k in [0,256)=[x|h]
__global__ __launch_bounds__(256) void k_prepw(const float* __restrict__ Wx, const float* __restrict__ Wh,
                                               short* __restrict__ Wt){
  int n = blockIdx.x;       // 0..511
  int k = threadIdx.x;      // 0..255
  int g = n >> 7, j = n & 127;
  float v;
  if (g == 0)      v = (k < 128) ? Wx[k*384 + j]       : Wh[(k-128)*384 + j];
  else if (g == 1) v = (k < 128) ? Wx[k*384 + 128 + j] : Wh[(k-128)*384 + 128 + j];
  else if (g == 2) v = (k < 128) ? Wx[k*384 + 256 + j] : 0.f;
  else             v = (k < 128) ? 0.f                 : Wh[(k-128)*384 + 256 + j];
  Wt[n*256 + k] = f2bf(v);
}

// MFMA GRU: 64 edge-rows per block, A=[tanh(nmsg+ne gathered) | h] bf16 in LDS,
// B = Wt streamed from global. Wave w owns gate-cols [32w,32w+32) across all 4 groups.
__global__ __launch_bounds__(256) void k_gru_mfma(const float* __restrict__ ne, const float* __restrict__ nmsg,
    const int* __restrict__ adj, const short* __restrict__ Wt, const float* __restrict__ bgru,
    float* __restrict__ h){
  __shared__ short As[64][264];   // +8 pad: 528B row stride -> 2-way bank aliasing (free)
  int tid = threadIdx.x;
  int ge0 = blockIdx.x*64;
  // ---- stage A tile ----
  {
    int i = tid >> 2, seg = tid & 3;
    int ge = ge0 + i;
    int nv = ge >> 4, d = ge & 15;
    if (seg < 2){
      int a = adj[nv*16 + d];
      int bb = nv >> 10;
      const float4* pm = reinterpret_cast<const float4*>(&nmsg[((bb<<10) + a)*128]);
      const float4* pe = reinterpret_cast<const float4*>(&ne[((bb<<10) + a)*128]);
      #pragma unroll 4
      for (int e=0;e<16;e++){
        int j4 = seg*16 + e;
        float4 m4 = pm[j4], e4 = pe[j4];
        short4 s;
        s.x = f2bf(tanhf(m4.x+e4.x)); s.y = f2bf(tanhf(m4.y+e4.y));
        s.z = f2bf(tanhf(m4.z+e4.z)); s.w = f2bf(tanhf(m4.w+e4.w));
        *reinterpret_cast<short4*>(&As[i][j4*4]) = s;
      }
    } else {
      const float4* ph = reinterpret_cast<const float4*>(&h[ge*128]);
      #pragma unroll 4
      for (int e=0;e<16;e++){
        int j4 = (seg-2)*16 + e;
        float4 h4 = ph[j4];
        short4 s;
        s.x = f2bf(h4.x); s.y = f2bf(h4.y); s.z = f2bf(h4.z); s.w = f2bf(h4.w);
        *reinterpret_cast<short4*>(&As[i][128 + j4*4]) = s;
      }
    }
  }
  __syncthreads();
  int w = tid >> 6, lane = tid & 63;
  int l15 = lane & 15, quad = lane >> 4;
  f32x4 acc[4][4][2];   // [m-tile][group z,r,cx,ch][u]
  #pragma unroll
  for (int mt=0;mt<4;mt++)
    #pragma unroll
    for (int g=0;g<4;g++)
      #pragma unroll
      for (int u=0;u<2;u++) acc[mt][g][u] = (f32x4){0.f,0.f,0.f,0.f};

  for (int k8=0;k8<8;k8++){
    int k0 = k8*32;
    int gg = (k8 < 4) ? 2 : 3;
    bf16x8 a[4];
    #pragma unroll
    for (int mt=0;mt<4;mt++)
      a[mt] = *reinterpret_cast<const bf16x8*>(&As[16*mt + l15][k0 + quad*8]);
    bf16x8 bz[2], br[2], bc[2];
    #pragma unroll
    for (int u=0;u<2;u++){
      int ncol = 32*w + 16*u + l15;
      int koff = k0 + quad*8;
      bz[u] = *reinterpret_cast<const bf16x8*>(&Wt[(ncol      )*256 + koff]);
      br[u] = *reinterpret_cast<const bf16x8*>(&Wt[(ncol + 128)*256 + koff]);
      bc[u] = *reinterpret_cast<const bf16x8*>(&Wt[(ncol + gg*128)*256 + koff]);
    }
    #pragma unroll
    for (int mt=0;mt<4;mt++){
      #pragma unroll
      for (int u=0;u<2;u++){
        acc[mt][0][u]  = __builtin_amdgcn_mfma_f32_16x16x32_bf16(a[mt], bz[u], acc[mt][0][u], 0,0,0);
        acc[mt][1][u]  = __builtin_amdgcn_mfma_f32_16x16x32_bf16(a[mt], br[u], acc[mt][1][u], 0,0,0);
        acc[mt][gg][u] = __builtin_amdgcn_mfma_f32_16x16x32_bf16(a[mt], bc[u], acc[mt][gg][u], 0,0,0);
      }
    }
  }
  // ---- epilogue: GRU gates, h update (h re-read in fp32 for accuracy) ----
  #pragma unroll
  for (int u=0;u<2;u++){
    int j = 32*w + 16*u + l15;
    float bjz = bgru[j], bjr = bgru[128 + j], bjc = bgru[256 + j];
    #pragma unroll
    for (int mt=0;mt<4;mt++){
      #pragma unroll
      for (int reg=0;reg<4;reg++){
        int row = ge0 + 16*mt + quad*4 + reg;
        float z = 1.f/(1.f + expf(-(acc[mt][0][u][reg] + bjz)));
        float r = 1.f/(1.f + expf(-(acc[mt][1][u][reg] + bjr)));
        float cand = tanhf(acc[mt][2][u][reg] + bjc + r*acc[mt][3][u][reg]);
        float ho = h[row*H + j];
        h[row*H + j] = z*ho + (1.f - z)*cand;
      }
    }
  }
}

// Decoder per half-node: dec_in=[h | h + h_opp]; nw = tanh(dec_in@W1+b1)@W2+b2
__global__ __launch_bounds__(64) void k_dec(const float* __restrict__ h, const int* __restrict__ adj,
    const float* __restrict__ W1, const float* __restrict__ b1, const float* __restrict__ W2,
    const float* __restrict__ b2_, float* __restrict__ nw){
  __shared__ float din[8][256];
  int tid = threadIdx.x;
  int blk = blockIdx.x;
  int node = blk >> 1, half = blk & 1, b = node >> 10;
  int dbase = half*8;
  for (int idx=tid; idx<8*256; idx+=64){
    int i = idx >> 8, q = idx & 255;
    int d = dbase + i;
    float hv = h[(node*D + d)*H + (q & 127)];
    if (q < 128){
      din[i][q] = hv;
    } else {
      int a = adj[node*D + d];
      int od = d ^ 1;
      din[i][q] = hv + h[((b*V + a)*D + od)*H + (q-128)];
    }
  }
  __syncthreads();
  int c = tid;
  float acc[8] = {0,0,0,0,0,0,0,0};
  for (int kk=0; kk<256; kk+=4){
    float w[4];
    #pragma unroll
    for (int u=0;u<4;u++) w[u] = W1[(kk+u)*HD + c];
    #pragma unroll
    for (int i=0;i<8;i++){
      const float4 v = *reinterpret_cast<const float4*>(&din[i][kk]);
      acc[i] += v.x*w[0]+v.y*w[1]+v.z*w[2]+v.w*w[3];
    }
  }
  float bd = b1[c];
  float w2 = W2[c];
  float b2v = b2_[0];
  #pragma unroll
  for (int i=0;i<8;i++){
    float t = tanhf(acc[i] + bd) * w2;
    #pragma unroll
    for (int off=32; off>0; off>>=1) t += __shfl_down(t, off);
    if (tid == 0) nw[node*D + dbase + i] = t + b2v;
  }
}

// dest_attn = softmax_d( nw[b, inv_adj[v,d], d] )
__global__ __launch_bounds__(256) void k_dattn(const float* __restrict__ nw, const int* __restrict__ invadj,
                                               float* __restrict__ dattn){
  int node = blockIdx.x*256 + threadIdx.x;
  if (node >= BV) return;
  int b = node >> 10;
  float vals[16];
  #pragma unroll
  for (int d=0; d<16; d++){
    int ia = invadj[node*D + d];
    vals[d] = nw[(b*V + ia)*D + d];
  }
  float m = vals[0];
  #pragma unroll
  for (int d=1; d<16; d++) m = fmaxf(m, vals[d]);
  float s = 0.f;
  #pragma unroll
  for (int d=0; d<16; d++){ vals[d] = expf(vals[d]-m); s += vals[d]; }
  float inv = 1.f/s;
  #pragma unroll
  for (int d=0; d<16; d++) dattn[node*D + d] = vals[d]*inv;
}

// normalized = sparsemax_d( dattn[b, adj[v,d], d] )
__global__ __launch_bounds__(256) void k_sparse(const float* __restrict__ dattn, const int* __restrict__ adj,
                                                float* __restrict__ norm_){
  int node = blockIdx.x*256 + threadIdx.x;
  if (node >= BV) return;
  int b = node >> 10;
  float z[16], s[16];
  #pragma unroll
  for (int d=0; d<16; d++){
    int a = adj[node*D + d];
    z[d] = dattn[(b*V + a)*D + d];
    s[d] = z[d];
  }
  #pragma unroll
  for (int k2 = 2; k2 <= 16; k2 <<= 1){
    #pragma unroll
    for (int jj = k2 >> 1; jj > 0; jj >>= 1){
      #pragma unroll
      for (int i = 0; i < 16; i++){
        int l = i ^ jj;
        if (l > i){
          bool up = ((i & k2) == 0);
          float a = s[i], bb = s[l];
          bool sw = up ? (a > bb) : (a < bb);
          if (sw){ s[i]=bb; s[l]=a; }
        }
      }
    }
  }
  float cs = 0.f, zcs = 0.f; int kz = 1;
  #pragma unroll
  for (int j=0;j<16;j++){
    float zj = s[15-j];   // descending
    cs += zj;
    if (1.f + (float)(j+1)*zj > cs){ kz = j+1; zcs = cs; }
  }
  float tau = (zcs - 1.f)/(float)kz;
  #pragma unroll
  for (int d=0; d<16; d++) norm_[node*D + d] = fmaxf(z[d]-tau, 0.f);
}

// one MCF iteration
__global__ __launch_bounds__(256) void k_flow(const float* __restrict__ fprev, const float* __restrict__ norm_,
    const float* __restrict__ dem, const int* __restrict__ invadj, float* __restrict__ fnext){
  int node = blockIdx.x*256 + threadIdx.x;
  if (node >= BV) return;
  int b = node >> 10;
  float inflow = 0.f;
  #pragma unroll
  for (int d=0; d<16; d++){
    int ia = invadj[node*D + d];
    inflow += fprev[(b*V + ia)*D + d];
  }
  float s = fmaxf(inflow - dem[node], 0.f);
  #pragma unroll
  for (int d=0; d<16; d++) fnext[node*D + d] = norm_[node*D + d]*s;
}

// dual_vars per node + dual_demand accumulation
__global__ __launch_bounds__(128) void k_dualvars(const float* __restrict__ h, const float* __restrict__ W1,
    const float* __restrict__ b1, const float* __restrict__ W2, const float* __restrict__ b2_,
    const float* __restrict__ dem, float* __restrict__ dv, float* __restrict__ accdd){
  __shared__ float ns[128];
  int node = blockIdx.x; int b = node >> 10;
  int tid = threadIdx.x;
  float s = 0.f;
  #pragma unroll
  for (int d=0; d<16; d++) s += h[(node*D + d)*H + tid];
  ns[tid] = s;
  __syncthreads();
  if (tid < 64){
    float acc = 0.f;
    for (int k=0;k<128;k++) acc += ns[k]*W1[k*HD + tid];
    float t = tanhf(acc + b1[tid]) * W2[tid];
    #pragma unroll
    for (int off=32; off>0; off>>=1) t += __shfl_down(t, off);
    if (tid == 0){
      float val = fmaxf(t + b2_[0], 0.f);
      dv[node] = val;
      atomicAdd(&accdd[b], val * dem[node]);
    }
  }
}

// flow cost + dual flow iterations + dual cost
__global__ __launch_bounds__(256) void k_cost(const float* __restrict__ flow, const float* __restrict__ dv,
    const int* __restrict__ adj, float* __restrict__ accF, float* __restrict__ accD){
  int gid = blockIdx.x*256 + threadIdx.x;
  int b = gid >> 14;          // V*D = 16384
  int a = adj[gid];
  float diff = dv[b*V + a];
  float f = 0.f, vel = 0.f;
  #pragma unroll
  for (int it=0; it<10; it++){
    float g = 2.f*f + diff;
    vel = 0.9f*vel - 0.01f*g;
    f = fmaxf(f + vel, 0.f);
  }
  float cd = f*f + diff*f;
  float fl = flow[gid];
  float cf = fl*fl;
  #pragma unroll
  for (int off=32; off>0; off>>=1){ cd += __shfl_down(cd, off); cf += __shfl_down(cf, off); }
  __shared__ float r1[4], r2[4];
  int lane = threadIdx.x & 63, w = threadIdx.x >> 6;
  if (lane==0){ r1[w]=cf; r2[w]=cd; }
  __syncthreads();
  if (threadIdx.x==0){
    atomicAdd(&accF[b], r1[0]+r1[1]+r1[2]+r1[3]);
    atomicAdd(&accD[b], r2[0]+r2[1]+r2[2]+r2[3]);
  }
}

__global__ __launch_bounds__(64) void k_final(const float* __restrict__ acc, float* __restrict__ out){
  int b = threadIdx.x;
  if (b < B){
    float fc = acc[b], dc = acc[16+b], dd = acc[32+b];
    out[b] = fc - (dc - dd);
  }
}

extern "C" void kernel_launch(void* const* d_in, const int* in_sizes, int n_in,
                              void* d_out, int out_size, void* d_ws, size_t ws_size,
                              hipStream_t stream){
  (void)in_sizes; (void)n_in; (void)out_size; (void)ws_size;
  const float* demands = (const float*)d_in[0];
  const float* nf      = (const float*)d_in[1];
  const float* emb     = (const float*)d_in[4];
  const float* Wenc    = (const float*)d_in[5];
  const float* benc    = (const float*)d_in[6];
  const float* Wgat    = (const float*)d_in[7];
  const float* bgat    = (const float*)d_in[8];
  const float* agat    = (const float*)d_in[9];
  const float* Wgx     = (const float*)d_in[10];
  const float* Wgh     = (const float*)d_in[11];
  const float* bgru    = (const float*)d_in[12];
  const float* Wd1     = (const float*)d_in[13];
  const float* bd1     = (const float*)d_in[14];
  const float* Wd2     = (const float*)d_in[15];
  const float* bd2     = (const float*)d_in[16];
  const float* Wu1     = (const float*)d_in[17];
  const float* bu1     = (const float*)d_in[18];
  const float* Wu2     = (const float*)d_in[19];
  const float* bu2     = (const float*)d_in[20];
  const int* adj       = (const int*)d_in[21];
  const int* invadj    = (const int*)d_in[22];

  float* ws    = (float*)d_ws;
  float* ne    = ws + OFF_NODE_ENC;
  float* h     = ws + OFF_H;
  float* nmsg  = ws + OFF_NMSG;
  float* embn  = ws + OFF_EMB;
  float* nw    = ws + OFF_NW;
  float* dattn = ws + OFF_DATTN;
  float* nrm   = ws + OFF_NORM;
  float* fa    = ws + OFF_FLOWA;
  float* fb    = ws + OFF_FLOWB;
  float* dv    = ws + OFF_DV;
  float* acc   = ws + OFF_ACC;
  short* wt    = (short*)(ws + OFF_WT);

  k_zero<<<(ZERO_COUNT+255)/256, 256, 0, stream>>>(ws);
  k_embnorm<<<V, 64, 0, stream>>>(emb, embn);
  k_prepw<<<512, 256, 0, stream>>>(Wgx, Wgh, wt);
  k_enc<<<BV/16, 256, 0, stream>>>(embn, nf, Wenc, benc, ne);
  k_hinit<<<BV, 256, 0, stream>>>(ne, adj, h);
  for (int layer=0; layer<2; layer++){
    k_gat<<<BV, 64, 0, stream>>>(h, Wgat, bgat, agat, nmsg);
    k_gru_mfma<<<BVD/64, 256, 0, stream>>>(ne, nmsg, adj, wt, bgru, h);
  }
  k_dec<<<BV*2, 64, 0, stream>>>(h, adj, Wd1, bd1, Wd2, bd2, nw);
  k_dattn<<<BV/256, 256, 0, stream>>>(nw, invadj, dattn);
  k_sparse<<<BV/256, 256, 0, stream>>>(dattn, adj, nrm);
  float* src = fa; float* dst = fb;
  for (int it=0; it<10; it++){
    k_flow<<<BV/256, 256, 0, stream>>>(src, nrm, demands, invadj, dst);
    float* t = dst; dst = src; src = t;
  }
  k_dualvars<<<BV, 128, 0, stream>>>(h, Wu1, bu1, Wu2, bu2, demands, dv, acc+32);
  k_cost<<<BVD/256, 256, 0, stream>>>(src, dv, adj, acc, acc+16);
  k_final<<<1, 64, 0, stream>>>(acc, (float*)d_out);
}

// Round 4
// 1146.224 us; speedup vs baseline: 2.9380x; 1.3787x over previous
//
#include <hip/hip_runtime.h>
#include <hip/hip_bf16.h>

#define B 16
#define V 1024
#define D 16
#define E 64
#define F 16
#define H 128
#define HD 64
#define BV (B*V)      // 16384
#define BVD (B*V*D)   // 262144

// ---- workspace layout (float offsets) ----
#define OFF_NODE_ENC 0
#define OFF_H        (OFF_NODE_ENC + BV*H)     // h edge states (B,V,D,H) fp32
#define OFF_NMSG     (OFF_H + BVD*H)
#define OFF_EMB      (OFF_NMSG + BV*H)
#define OFF_NW       (OFF_EMB + V*E)
#define OFF_DATTN    (OFF_NW + BVD)
#define OFF_NORM     (OFF_DATTN + BVD)
#define OFF_FLOWA    (OFF_NORM + BVD)
#define OFF_DV       (OFF_FLOWA + BVD)
#define OFF_ACC      (OFF_DV + BV)             // [0:16) flow_cost, [16:32) dual, [32:48) dual_demand
#define OFF_WT       (OFF_ACC + 64)            // 512x256 bf16 GRU weights   = 65536 floats
#define OFF_WTG      (OFF_WT + 65536)          // 128x128 bf16 GAT weights   = 8192 floats
#define OFF_WTD      (OFF_WTG + 8192)          // 64x256  bf16 dec weights   = 8192 floats

typedef __attribute__((ext_vector_type(8))) short bf16x8;
typedef __attribute__((ext_vector_type(4))) float f32x4;

__device__ __forceinline__ short f2bf(float f){
  __hip_bfloat16 b = __float2bfloat16(f);
  return *reinterpret_cast<short*>(&b);
}

__global__ __launch_bounds__(64) void k_zero_acc(float* acc){
  acc[threadIdx.x] = 0.f;
}

// embedding max_norm=1 normalization: (V,E) -> f32
__global__ __launch_bounds__(64) void k_embnorm(const float* __restrict__ emb, float* __restrict__ embn){
  int v = blockIdx.x, e = threadIdx.x;
  float val = emb[v*E + e];
  float ss = val*val;
  #pragma unroll
  for (int off=32; off>0; off>>=1) ss += __shfl_down(ss, off);
  ss = __shfl(ss, 0);
  float scale = 1.f / fmaxf(sqrtf(ss), 1.f);
  embn[v*E + e] = val * scale;
}

// pack GRU weights bf16 n-major: Wt[n][k], n in [0,512): groups z,r,cx,ch; k in [0,256)=[x|h]
__global__ __launch_bounds__(256) void k_prepw(const float* __restrict__ Wx, const float* __restrict__ Wh,
                                               short* __restrict__ Wt){
  int n = blockIdx.x;       // 0..511
  int k = threadIdx.x;      // 0..255
  int g = n >> 7, j = n & 127;
  float v;
  if (g == 0)      v = (k < 128) ? Wx[k*384 + j]       : Wh[(k-128)*384 + j];
  else if (g == 1) v = (k < 128) ? Wx[k*384 + 128 + j] : Wh[(k-128)*384 + 128 + j];
  else if (g == 2) v = (k < 128) ? Wx[k*384 + 256 + j] : 0.f;
  else             v = (k < 128) ? 0.f                 : Wh[(k-128)*384 + 256 + j];
  Wt[n*256 + k] = f2bf(v);
}

// pack GAT weight transposed bf16: Wgt[n][k] = Wg[k][n]
__global__ __launch_bounds__(128) void k_prepg(const float* __restrict__ Wg, short* __restrict__ Wgt){
  int n = blockIdx.x, k = threadIdx.x;
  Wgt[n*128 + k] = f2bf(Wg[k*128 + n]);
}

// pack decoder W1 transposed bf16: W1t[n][k] = W1[k][n], n<64, k<256
__global__ __launch_bounds__(256) void k_prepd(const float* __restrict__ W1, short* __restrict__ W1t){
  int n = blockIdx.x, k = threadIdx.x;
  W1t[n*256 + k] = f2bf(W1[k*64 + n]);
}

// node_enc = [emb_n | node_features] @ W_enc + b_enc   (M=BV, K=80, N=128)
__global__ __launch_bounds__(256) void k_enc(const float* __restrict__ embn, const float* __restrict__ nf,
                                             const float* __restrict__ Wenc, const float* __restrict__ benc,
                                             float* __restrict__ ne){
  __shared__ float As[16][80];
  int tid = threadIdx.x;
  int m0 = blockIdx.x*16;
  for (int idx=tid; idx<16*80; idx+=256){
    int i = idx/80, k = idx%80;
    int m = m0 + i; int v = m & (V-1);
    As[i][k] = (k < E) ? embn[v*E + k] : nf[m*F + (k-E)];
  }
  __syncthreads();
  int c = tid & 127, half = tid >> 7;
  float acc[8] = {0,0,0,0,0,0,0,0};
  for (int kk=0; kk<80; kk+=4){
    float w[4];
    #pragma unroll
    for (int u=0;u<4;u++) w[u] = Wenc[(kk+u)*H + c];
    #pragma unroll
    for (int i=0;i<8;i++){
      const float4 av = *reinterpret_cast<const float4*>(&As[half*8+i][kk]);
      acc[i] += av.x*w[0] + av.y*w[1] + av.z*w[2] + av.w*w[3];
    }
  }
  float bb = benc[c];
  #pragma unroll
  for (int i=0;i<8;i++){
    int m = m0 + half*8 + i;
    ne[m*H + c] = acc[i] + bb;
  }
}

// h init = gather(node_enc, adj)
__global__ __launch_bounds__(256) void k_hinit(const float* __restrict__ ne, const int* __restrict__ adj,
                                               float* __restrict__ h){
  int node = blockIdx.x; int b = node >> 10;
  for (int idx=threadIdx.x; idx<D*H/4; idx+=256){
    int d = idx >> 5, j4 = idx & 31;
    int a = adj[node*D + d];
    const float4 v = reinterpret_cast<const float4*>(&ne[(b*V + a)*H])[j4];
    reinterpret_cast<float4*>(&h[(node*D + d)*H])[j4] = v;
  }
}

// MFMA DirectionalGAT: wave-per-node. t=tanh(h@Wg+bg) via 16x16x32 MFMA,
// softmax-attention epilogue entirely in registers via shfl_xor butterflies.
__global__ __launch_bounds__(256) void k_gat_mfma(const float* __restrict__ h, const short* __restrict__ Wgt,
    const float* __restrict__ bg, const float* __restrict__ ag, float* __restrict__ nmsg){
  __shared__ short As[4][16][136];
  int tid = threadIdx.x;
  int w = tid >> 6, lane = tid & 63;
  int node = blockIdx.x*4 + w;
  // stage node's 16x128 h tile -> bf16 LDS, contiguous mapping
  const float4* ph = reinterpret_cast<const float4*>(&h[node*16*128]);
  #pragma unroll
  for (int e=0;e<8;e++){
    int idx = e*64 + lane;          // 0..511 float4s
    int r = idx >> 5, j4 = idx & 31;
    float4 v = ph[idx];
    short4 s; s.x=f2bf(v.x); s.y=f2bf(v.y); s.z=f2bf(v.z); s.w=f2bf(v.w);
    *reinterpret_cast<short4*>(&As[w][r][j4*4]) = s;
  }
  __syncthreads();
  int l15 = lane & 15, quad = lane >> 4;
  f32x4 acc[8];
  #pragma unroll
  for (int u=0;u<8;u++) acc[u] = (f32x4){0.f,0.f,0.f,0.f};
  #pragma unroll
  for (int kc=0; kc<4; kc++){
    int k0 = kc*32;
    bf16x8 a = *reinterpret_cast<const bf16x8*>(&As[w][l15][k0 + quad*8]);
    #pragma unroll
    for (int u=0;u<8;u++){
      bf16x8 bfr = *reinterpret_cast<const bf16x8*>(&Wgt[(16*u + l15)*128 + k0 + quad*8]);
      acc[u] = __builtin_amdgcn_mfma_f32_16x16x32_bf16(a, bfr, acc[u], 0,0,0);
    }
  }
  // epilogue: tanh, logits, softmax, attention-weighted msg — all in registers
  float tv[8][4];
  float lp[4] = {0.f,0.f,0.f,0.f};
  #pragma unroll
  for (int u=0;u<8;u++){
    int c = 16*u + l15;
    float bgc = bg[c], agc = ag[c];
    #pragma unroll
    for (int reg=0;reg<4;reg++){
      float t = tanhf(acc[u][reg] + bgc);
      tv[u][reg] = t;
      lp[reg] += t * agc;
    }
  }
  #pragma unroll
  for (int reg=0;reg<4;reg++){
    lp[reg] += __shfl_xor(lp[reg], 1);
    lp[reg] += __shfl_xor(lp[reg], 2);
    lp[reg] += __shfl_xor(lp[reg], 4);
    lp[reg] += __shfl_xor(lp[reg], 8);
  }
  // lp[reg] = logit of row quad*4+reg (replicated across the 16-lane group)
  float m4 = fmaxf(fmaxf(lp[0],lp[1]), fmaxf(lp[2],lp[3]));
  m4 = fmaxf(m4, __shfl_xor(m4, 16));
  m4 = fmaxf(m4, __shfl_xor(m4, 32));
  float e4[4]; float s4 = 0.f;
  #pragma unroll
  for (int reg=0;reg<4;reg++){ e4[reg] = expf(lp[reg]-m4); s4 += e4[reg]; }
  s4 += __shfl_xor(s4, 16);
  s4 += __shfl_xor(s4, 32);
  float inv = 1.f/s4;
  #pragma unroll
  for (int reg=0;reg<4;reg++) e4[reg] *= inv;     // attn for own 4 rows
  #pragma unroll
  for (int u=0;u<8;u++){
    float mp = e4[0]*tv[u][0] + e4[1]*tv[u][1] + e4[2]*tv[u][2] + e4[3]*tv[u][3];
    mp += __shfl_xor(mp, 16);
    mp += __shfl_xor(mp, 32);
    if (quad == 0) nmsg[node*128 + 16*u + l15] = mp;
  }
}

// MFMA GRU: 64 edge-rows per block, A=[tanh(nmsg+ne gathered) | h] bf16 in LDS,
// B = Wt streamed from global. Wave w owns gate-cols [32w,32w+32) across groups.
__global__ __launch_bounds__(256) void k_gru_mfma(const float* __restrict__ ne, const float* __restrict__ nmsg,
    const int* __restrict__ adj, const short* __restrict__ Wt, const float* __restrict__ bgru,
    float* __restrict__ h){
  __shared__ short As[64][264];
  int tid = threadIdx.x;
  int ge0 = blockIdx.x*64;
  {
    int i = tid >> 2, seg = tid & 3;
    int ge = ge0 + i;
    int nv = ge >> 4, d = ge & 15;
    if (seg < 2){
      int a = adj[nv*16 + d];
      int bb = nv >> 10;
      const float4* pm = reinterpret_cast<const float4*>(&nmsg[((bb<<10) + a)*128]);
      const float4* pe = reinterpret_cast<const float4*>(&ne[((bb<<10) + a)*128]);
      #pragma unroll 4
      for (int e=0;e<16;e++){
        int j4 = seg*16 + e;
        float4 m4 = pm[j4], e4 = pe[j4];
        short4 s;
        s.x = f2bf(tanhf(m4.x+e4.x)); s.y = f2bf(tanhf(m4.y+e4.y));
        s.z = f2bf(tanhf(m4.z+e4.z)); s.w = f2bf(tanhf(m4.w+e4.w));
        *reinterpret_cast<short4*>(&As[i][j4*4]) = s;
      }
    } else {
      const float4* ph = reinterpret_cast<const float4*>(&h[ge*128]);
      #pragma unroll 4
      for (int e=0;e<16;e++){
        int j4 = (seg-2)*16 + e;
        float4 h4 = ph[j4];
        short4 s;
        s.x = f2bf(h4.x); s.y = f2bf(h4.y); s.z = f2bf(h4.z); s.w = f2bf(h4.w);
        *reinterpret_cast<short4*>(&As[i][128 + j4*4]) = s;
      }
    }
  }
  __syncthreads();
  int w = tid >> 6, lane = tid & 63;
  int l15 = lane & 15, quad = lane >> 4;
  f32x4 acc[4][4][2];
  #pragma unroll
  for (int mt=0;mt<4;mt++)
    #pragma unroll
    for (int g=0;g<4;g++)
      #pragma unroll
      for (int u=0;u<2;u++) acc[mt][g][u] = (f32x4){0.f,0.f,0.f,0.f};

  for (int k8=0;k8<8;k8++){
    int k0 = k8*32;
    int gg = (k8 < 4) ? 2 : 3;
    bf16x8 a[4];
    #pragma unroll
    for (int mt=0;mt<4;mt++)
      a[mt] = *reinterpret_cast<const bf16x8*>(&As[16*mt + l15][k0 + quad*8]);
    bf16x8 bz[2], br[2], bc[2];
    #pragma unroll
    for (int u=0;u<2;u++){
      int ncol = 32*w + 16*u + l15;
      int koff = k0 + quad*8;
      bz[u] = *reinterpret_cast<const bf16x8*>(&Wt[(ncol      )*256 + koff]);
      br[u] = *reinterpret_cast<const bf16x8*>(&Wt[(ncol + 128)*256 + koff]);
      bc[u] = *reinterpret_cast<const bf16x8*>(&Wt[(ncol + gg*128)*256 + koff]);
    }
    #pragma unroll
    for (int mt=0;mt<4;mt++){
      #pragma unroll
      for (int u=0;u<2;u++){
        acc[mt][0][u]  = __builtin_amdgcn_mfma_f32_16x16x32_bf16(a[mt], bz[u], acc[mt][0][u], 0,0,0);
        acc[mt][1][u]  = __builtin_amdgcn_mfma_f32_16x16x32_bf16(a[mt], br[u], acc[mt][1][u], 0,0,0);
        acc[mt][gg][u] = __builtin_amdgcn_mfma_f32_16x16x32_bf16(a[mt], bc[u], acc[mt][gg][u], 0,0,0);
      }
    }
  }
  #pragma unroll
  for (int u=0;u<2;u++){
    int j = 32*w + 16*u + l15;
    float bjz = bgru[j], bjr = bgru[128 + j], bjc = bgru[256 + j];
    #pragma unroll
    for (int mt=0;mt<4;mt++){
      #pragma unroll
      for (int reg=0;reg<4;reg++){
        int row = ge0 + 16*mt + quad*4 + reg;
        float z = 1.f/(1.f + expf(-(acc[mt][0][u][reg] + bjz)));
        float r = 1.f/(1.f + expf(-(acc[mt][1][u][reg] + bjr)));
        float cand = tanhf(acc[mt][2][u][reg] + bjc + r*acc[mt][3][u][reg]);
        float ho = h[row*H + j];
        h[row*H + j] = z*ho + (1.f - z)*cand;
      }
    }
  }
}

// MFMA decoder: wave-per-16-edges. dec_in=[h | h+h_opp] (K=256) @ W1t (N=64),
// tanh, *W2 column-reduce via shfl butterfly, +b2 -> nw per edge.
__global__ __launch_bounds__(256) void k_dec_mfma(const float* __restrict__ h, const int* __restrict__ adj,
    const short* __restrict__ W1t, const float* __restrict__ b1, const float* __restrict__ W2,
    const float* __restrict__ b2_, float* __restrict__ nw){
  __shared__ short Ds[4][16][264];
  int tid = threadIdx.x;
  int w = tid >> 6, lane = tid & 63;
  int ge0 = blockIdx.x*64 + w*16;
  {
    int r = lane >> 2, seg = lane & 3;
    int ge = ge0 + r;
    int nv = ge >> 4, d = ge & 15, b = nv >> 10;
    int a = adj[nv*16 + d];
    int opp = ((((b<<10) + a)<<4) + (d^1));
    const float4* po = reinterpret_cast<const float4*>(&h[ge*128]);
    const float4* pp = reinterpret_cast<const float4*>(&h[opp*128]);
    #pragma unroll
    for (int e=0;e<8;e++){
      int j4 = seg*8 + e;
      float4 ov = po[j4], pv = pp[j4];
      short4 s1; s1.x=f2bf(ov.x); s1.y=f2bf(ov.y); s1.z=f2bf(ov.z); s1.w=f2bf(ov.w);
      *reinterpret_cast<short4*>(&Ds[w][r][j4*4]) = s1;
      short4 s2; s2.x=f2bf(ov.x+pv.x); s2.y=f2bf(ov.y+pv.y); s2.z=f2bf(ov.z+pv.z); s2.w=f2bf(ov.w+pv.w);
      *reinterpret_cast<short4*>(&Ds[w][r][128 + j4*4]) = s2;
    }
  }
  __syncthreads();
  int l15 = lane & 15, quad = lane >> 4;
  f32x4 acc[4];
  #pragma unroll
  for (int u=0;u<4;u++) acc[u] = (f32x4){0.f,0.f,0.f,0.f};
  #pragma unroll
  for (int kc=0;kc<8;kc++){
    int k0 = kc*32;
    bf16x8 av = *reinterpret_cast<const bf16x8*>(&Ds[w][l15][k0 + quad*8]);
    #pragma unroll
    for (int u=0;u<4;u++){
      bf16x8 bfr = *reinterpret_cast<const bf16x8*>(&W1t[(16*u + l15)*256 + k0 + quad*8]);
      acc[u] = __builtin_amdgcn_mfma_f32_16x16x32_bf16(av, bfr, acc[u], 0,0,0);
    }
  }
  float p[4] = {0.f,0.f,0.f,0.f};
  #pragma unroll
  for (int u=0;u<4;u++){
    int c = 16*u + l15;
    float bc = b1[c], wc = W2[c];
    #pragma unroll
    for (int reg=0;reg<4;reg++) p[reg] += tanhf(acc[u][reg] + bc) * wc;
  }
  #pragma unroll
  for (int reg=0;reg<4;reg++){
    p[reg] += __shfl_xor(p[reg], 1);
    p[reg] += __shfl_xor(p[reg], 2);
    p[reg] += __shfl_xor(p[reg], 4);
    p[reg] += __shfl_xor(p[reg], 8);
  }
  if (l15 == 0){
    float b2v = b2_[0];
    #pragma unroll
    for (int reg=0;reg<4;reg++) nw[ge0 + quad*4 + reg] = p[reg] + b2v;
  }
}

// dest_attn = softmax_d( nw[b, inv_adj[v,d], d] )
__global__ __launch_bounds__(256) void k_dattn(const float* __restrict__ nw, const int* __restrict__ invadj,
                                               float* __restrict__ dattn){
  int node = blockIdx.x*256 + threadIdx.x;
  if (node >= BV) return;
  int b = node >> 10;
  float vals[16];
  #pragma unroll
  for (int d=0; d<16; d++){
    int ia = invadj[node*D + d];
    vals[d] = nw[(b*V + ia)*D + d];
  }
  float m = vals[0];
  #pragma unroll
  for (int d=1; d<16; d++) m = fmaxf(m, vals[d]);
  float s = 0.f;
  #pragma unroll
  for (int d=0; d<16; d++){ vals[d] = expf(vals[d]-m); s += vals[d]; }
  float inv = 1.f/s;
  #pragma unroll
  for (int d=0; d<16; d++) dattn[node*D + d] = vals[d]*inv;
}

// normalized = sparsemax_d( dattn[b, adj[v,d], d] )
__global__ __launch_bounds__(256) void k_sparse(const float* __restrict__ dattn, const int* __restrict__ adj,
                                                float* __restrict__ norm_){
  int node = blockIdx.x*256 + threadIdx.x;
  if (node >= BV) return;
  int b = node >> 10;
  float z[16], s[16];
  #pragma unroll
  for (int d=0; d<16; d++){
    int a = adj[node*D + d];
    z[d] = dattn[(b*V + a)*D + d];
    s[d] = z[d];
  }
  #pragma unroll
  for (int k2 = 2; k2 <= 16; k2 <<= 1){
    #pragma unroll
    for (int jj = k2 >> 1; jj > 0; jj >>= 1){
      #pragma unroll
      for (int i = 0; i < 16; i++){
        int l = i ^ jj;
        if (l > i){
          bool up = ((i & k2) == 0);
          float a = s[i], bb = s[l];
          bool sw = up ? (a > bb) : (a < bb);
          if (sw){ s[i]=bb; s[l]=a; }
        }
      }
    }
  }
  float cs = 0.f, zcs = 0.f; int kz = 1;
  #pragma unroll
  for (int j=0;j<16;j++){
    float zj = s[15-j];
    cs += zj;
    if (1.f + (float)(j+1)*zj > cs){ kz = j+1; zcs = cs; }
  }
  float tau = (zcs - 1.f)/(float)kz;
  #pragma unroll
  for (int d=0; d<16; d++) norm_[node*D + d] = fmaxf(z[d]-tau, 0.f);
}

// all 10 MCF iterations fused: one block per batch, flow state in LDS (d-major
// layout -> stride-1 conflict-free gather AND scatter), invadj/norm in registers.
__global__ __launch_bounds__(1024) void k_flow_fused(const float* __restrict__ norm_,
    const float* __restrict__ dem, const int* __restrict__ invadj, float* __restrict__ flowout){
  __shared__ float fl[D*V];    // fl[d*V + v]
  int b = blockIdx.x, v = threadIdx.x;
  int base = ((b << 10) + v)*D;
  int ia[16]; float nr[16];
  #pragma unroll
  for (int d4=0; d4<4; d4++){
    int4 i4 = reinterpret_cast<const int4*>(&invadj[base])[d4];
    ia[d4*4+0]=i4.x; ia[d4*4+1]=i4.y; ia[d4*4+2]=i4.z; ia[d4*4+3]=i4.w;
    float4 n4 = reinterpret_cast<const float4*>(&norm_[base])[d4];
    nr[d4*4+0]=n4.x; nr[d4*4+1]=n4.y; nr[d4*4+2]=n4.z; nr[d4*4+3]=n4.w;
  }
  float dm = dem[(b<<10) + v];
  #pragma unroll
  for (int d=0; d<16; d++) fl[d*V + v] = 0.f;
  __syncthreads();
  float s = 0.f;
  for (int it=0; it<10; it++){
    float inflow = 0.f;
    #pragma unroll
    for (int d=0; d<16; d++) inflow += fl[d*V + ia[d]];
    __syncthreads();
    s = fmaxf(inflow - dm, 0.f);
    #pragma unroll
    for (int d=0; d<16; d++) fl[d*V + v] = nr[d]*s;
    __syncthreads();
  }
  #pragma unroll
  for (int d4=0; d4<4; d4++){
    float4 o;
    o.x = nr[d4*4+0]*s; o.y = nr[d4*4+1]*s; o.z = nr[d4*4+2]*s; o.w = nr[d4*4+3]*s;
    reinterpret_cast<float4*>(&flowout[base])[d4] = o;
  }
}

// dual_vars per node + dual_demand accumulation
__global__ __launch_bounds__(128) void k_dualvars(const float* __restrict__ h, const float* __restrict__ W1,
    const float* __restrict__ b1, const float* __restrict__ W2, const float* __restrict__ b2_,
    const float* __restrict__ dem, float* __restrict__ dv, float* __restrict__ accdd){
  __shared__ float ns[128];
  int node = blockIdx.x; int b = node >> 10;
  int tid = threadIdx.x;
  float s = 0.f;
  #pragma unroll
  for (int d=0; d<16; d++) s += h[(node*D + d)*H + tid];
  ns[tid] = s;
  __syncthreads();
  if (tid < 64){
    float acc = 0.f;
    for (int k=0;k<128;k++) acc += ns[k]*W1[k*HD + tid];
    float t = tanhf(acc + b1[tid]) * W2[tid];
    #pragma unroll
    for (int off=32; off>0; off>>=1) t += __shfl_down(t, off);
    if (tid == 0){
      float val = fmaxf(t + b2_[0], 0.f);
      dv[node] = val;
      atomicAdd(&accdd[b], val * dem[node]);
    }
  }
}

// flow cost + dual flow iterations + dual cost
__global__ __launch_bounds__(256) void k_cost(const float* __restrict__ flow, const float* __restrict__ dv,
    const int* __restrict__ adj, float* __restrict__ accF, float* __restrict__ accD){
  int gid = blockIdx.x*256 + threadIdx.x;
  int b = gid >> 14;
  int a = adj[gid];
  float diff = dv[b*V + a];
  float f = 0.f, vel = 0.f;
  #pragma unroll
  for (int it=0; it<10; it++){
    float g = 2.f*f + diff;
    vel = 0.9f*vel - 0.01f*g;
    f = fmaxf(f + vel, 0.f);
  }
  float cd = f*f + diff*f;
  float fl = flow[gid];
  float cf = fl*fl;
  #pragma unroll
  for (int off=32; off>0; off>>=1){ cd += __shfl_down(cd, off); cf += __shfl_down(cf, off); }
  __shared__ float r1[4], r2[4];
  int lane = threadIdx.x & 63, w = threadIdx.x >> 6;
  if (lane==0){ r1[w]=cf; r2[w]=cd; }
  __syncthreads();
  if (threadIdx.x==0){
    atomicAdd(&accF[b], r1[0]+r1[1]+r1[2]+r1[3]);
    atomicAdd(&accD[b], r2[0]+r2[1]+r2[2]+r2[3]);
  }
}

__global__ __launch_bounds__(64) void k_final(const float* __restrict__ acc, float* __restrict__ out){
  int b = threadIdx.x;
  if (b < B){
    float fc = acc[b], dc = acc[16+b], dd = acc[32+b];
    out[b] = fc - (dc - dd);
  }
}

extern "C" void kernel_launch(void* const* d_in, const int* in_sizes, int n_in,
                              void* d_out, int out_size, void* d_ws, size_t ws_size,
                              hipStream_t stream){
  (void)in_sizes; (void)n_in; (void)out_size; (void)ws_size;
  const float* demands = (const float*)d_in[0];
  const float* nf      = (const float*)d_in[1];
  const float* emb     = (const float*)d_in[4];
  const float* Wenc    = (const float*)d_in[5];
  const float* benc    = (const float*)d_in[6];
  const float* Wgat    = (const float*)d_in[7];
  const float* bgat    = (const float*)d_in[8];
  const float* agat    = (const float*)d_in[9];
  const float* Wgx     = (const float*)d_in[10];
  const float* Wgh     = (const float*)d_in[11];
  const float* bgru    = (const float*)d_in[12];
  const float* Wd1     = (const float*)d_in[13];
  const float* bd1     = (const float*)d_in[14];
  const float* Wd2     = (const float*)d_in[15];
  const float* bd2     = (const float*)d_in[16];
  const float* Wu1     = (const float*)d_in[17];
  const float* bu1     = (const float*)d_in[18];
  const float* Wu2     = (const float*)d_in[19];
  const float* bu2     = (const float*)d_in[20];
  const int* adj       = (const int*)d_in[21];
  const int* invadj    = (const int*)d_in[22];

  float* ws    = (float*)d_ws;
  float* ne    = ws + OFF_NODE_ENC;
  float* h     = ws + OFF_H;
  float* nmsg  = ws + OFF_NMSG;
  float* embn  = ws + OFF_EMB;
  float* nw    = ws + OFF_NW;
  float* dattn = ws + OFF_DATTN;
  float* nrm   = ws + OFF_NORM;
  float* fa    = ws + OFF_FLOWA;
  float* dv    = ws + OFF_DV;
  float* acc   = ws + OFF_ACC;
  short* wt    = (short*)(ws + OFF_WT);
  short* wtg   = (short*)(ws + OFF_WTG);
  short* wtd   = (short*)(ws + OFF_WTD);

  k_zero_acc<<<1, 64, 0, stream>>>(acc);
  k_embnorm<<<V, 64, 0, stream>>>(emb, embn);
  k_prepw<<<512, 256, 0, stream>>>(Wgx, Wgh, wt);
  k_prepg<<<128, 128, 0, stream>>>(Wgat, wtg);
  k_prepd<<<64, 256, 0, stream>>>(Wd1, wtd);
  k_enc<<<BV/16, 256, 0, stream>>>(embn, nf, Wenc, benc, ne);
  k_hinit<<<BV, 256, 0, stream>>>(ne, adj, h);
  for (int layer=0; layer<2; layer++){
    k_gat_mfma<<<BV/4, 256, 0, stream>>>(h, wtg, bgat, agat, nmsg);
    k_gru_mfma<<<BVD/64, 256, 0, stream>>>(ne, nmsg, adj, wt, bgru, h);
  }
  k_dec_mfma<<<BVD/64, 256, 0, stream>>>(h, adj, wtd, bd1, Wd2, bd2, nw);
  k_dattn<<<BV/256, 256, 0, stream>>>(nw, invadj, dattn);
  k_sparse<<<BV/256, 256, 0, stream>>>(dattn, adj, nrm);
  k_flow_fused<<<B, 1024, 0, stream>>>(nrm, demands, invadj, fa);
  k_dualvars<<<BV, 128, 0, stream>>>(h, Wu1, bu1, Wu2, bu2, demands, dv, acc+32);
  k_cost<<<BVD/256, 256, 0, stream>>>(fa, dv, adj, acc, acc+16);
  k_final<<<1, 64, 0, stream>>>(acc, (float*)d_out);
}

// Round 5
// 978.417 us; speedup vs baseline: 3.4419x; 1.1715x over previous
//
#include <hip/hip_runtime.h>
#include <hip/hip_bf16.h>

#define B 16
#define V 1024
#define D 16
#define E 64
#define F 16
#define H 128
#define HD 64
#define BV (B*V)      // 16384
#define BVD (B*V*D)   // 262144

// ---- workspace layout (float offsets) ----
#define OFF_NODE_ENC 0
#define OFF_H        (OFF_NODE_ENC + BV*H)     // h edge states (B,V,D,H) fp32
#define OFF_NMSG     (OFF_H + BVD*H)
#define OFF_EMB      (OFF_NMSG + BV*H)
#define OFF_NW       (OFF_EMB + V*E)
#define OFF_DATTN    (OFF_NW + BVD)
#define OFF_NORM     (OFF_DATTN + BVD)
#define OFF_FLOWA    (OFF_NORM + BVD)
#define OFF_DV       (OFF_FLOWA + BVD)
#define OFF_ACC      (OFF_DV + BV)             // [0:16) flow_cost, [16:32) dual, [32:48) dual_demand
#define OFF_WT       (OFF_ACC + 64)            // 512x256 bf16 GRU weights   = 65536 floats
#define OFF_WTG      (OFF_WT + 65536)          // 128x128 bf16 GAT weights   = 8192 floats
#define OFF_WTD      (OFF_WTG + 8192)          // 64x256  bf16 dec weights   = 8192 floats

typedef __attribute__((ext_vector_type(8))) short bf16x8;
typedef __attribute__((ext_vector_type(4))) float f32x4;

__device__ __forceinline__ short f2bf(float f){
  __hip_bfloat16 b = __float2bfloat16(f);
  return *reinterpret_cast<short*>(&b);
}
__device__ __forceinline__ float bf2f(short s){
  __hip_bfloat16 b; *reinterpret_cast<short*>(&b) = s;
  return __bfloat162float(b);
}
__device__ __forceinline__ float frcp(float x){ return __builtin_amdgcn_rcpf(x); }
// fast sigmoid: exp(-x) saturates to +inf/0 -> rcp gives correct 0/1 limits
__device__ __forceinline__ float fsig(float x){ return frcp(1.f + __expf(-x)); }
// fast tanh, NaN-safe: e in (0,1], no inf path
__device__ __forceinline__ float ftanh(float x){
  float e = __expf(-2.f*fabsf(x));
  float r = (1.f - e)*frcp(1.f + e);
  return copysignf(r, x);
}

// ---- merged prep: GRU/GAT/dec weight packs + embnorm + acc zero ----
// blocks: [0,512) prepw | [512,576) prepg | [576,640) prepd | [640,896) embnorm | 896 zero
__global__ __launch_bounds__(256) void k_prep(const float* __restrict__ Wx, const float* __restrict__ Wh,
    const float* __restrict__ Wg, const float* __restrict__ W1, const float* __restrict__ emb,
    short* __restrict__ Wt, short* __restrict__ Wgt, short* __restrict__ W1t,
    float* __restrict__ embn, float* __restrict__ acc){
  int bid = blockIdx.x, tid = threadIdx.x;
  if (bid < 512){
    int n = bid, k = tid;
    int g = n >> 7, j = n & 127;
    float v;
    if (g == 0)      v = (k < 128) ? Wx[k*384 + j]       : Wh[(k-128)*384 + j];
    else if (g == 1) v = (k < 128) ? Wx[k*384 + 128 + j] : Wh[(k-128)*384 + 128 + j];
    else if (g == 2) v = (k < 128) ? Wx[k*384 + 256 + j] : 0.f;
    else             v = (k < 128) ? 0.f                 : Wh[(k-128)*384 + 256 + j];
    Wt[n*256 + k] = f2bf(v);
  } else if (bid < 576){
    int idx = (bid-512)*256 + tid;       // 16384
    int n = idx >> 7, k = idx & 127;
    Wgt[n*128 + k] = f2bf(Wg[k*128 + n]);
  } else if (bid < 640){
    int n = bid - 576, k = tid;
    W1t[n*256 + k] = f2bf(W1[k*64 + n]);
  } else if (bid < 896){
    int v = (bid-640)*4 + (tid >> 6);
    int e = tid & 63;
    float val = emb[v*E + e];
    float ss = val*val;
    #pragma unroll
    for (int off=32; off>0; off>>=1) ss += __shfl_down(ss, off);
    ss = __shfl(ss, 0);
    embn[v*E + e] = val * frcp(fmaxf(sqrtf(ss), 1.f));
  } else {
    if (tid < 64) acc[tid] = 0.f;
  }
}

// node_enc = [emb_n | node_features] @ W_enc + b_enc   (M=BV, K=80, N=128)
__global__ __launch_bounds__(256) void k_enc(const float* __restrict__ embn, const float* __restrict__ nf,
                                             const float* __restrict__ Wenc, const float* __restrict__ benc,
                                             float* __restrict__ ne){
  __shared__ float As[16][80];
  int tid = threadIdx.x;
  int m0 = blockIdx.x*16;
  for (int idx=tid; idx<16*80; idx+=256){
    int i = idx/80, k = idx%80;
    int m = m0 + i; int v = m & (V-1);
    As[i][k] = (k < E) ? embn[v*E + k] : nf[m*F + (k-E)];
  }
  __syncthreads();
  int c = tid & 127, half = tid >> 7;
  float acc[8] = {0,0,0,0,0,0,0,0};
  for (int kk=0; kk<80; kk+=4){
    float w[4];
    #pragma unroll
    for (int u=0;u<4;u++) w[u] = Wenc[(kk+u)*H + c];
    #pragma unroll
    for (int i=0;i<8;i++){
      const float4 av = *reinterpret_cast<const float4*>(&As[half*8+i][kk]);
      acc[i] += av.x*w[0] + av.y*w[1] + av.z*w[2] + av.w*w[3];
    }
  }
  float bb = benc[c];
  #pragma unroll
  for (int i=0;i<8;i++){
    int m = m0 + half*8 + i;
    ne[m*H + c] = acc[i] + bb;
  }
}

// MFMA DirectionalGAT: wave-per-node. layer0: h := gather(ne, adj) read directly.
__global__ __launch_bounds__(256) void k_gat_mfma(const float* __restrict__ hsrc, const int* __restrict__ adj,
    const short* __restrict__ Wgt, const float* __restrict__ bg, const float* __restrict__ ag,
    float* __restrict__ nmsg, int gather0){
  __shared__ short As[4][16][136];
  int tid = threadIdx.x;
  int w = tid >> 6, lane = tid & 63;
  int node = blockIdx.x*4 + w;
  int b = node >> 10;
  // stage 16x128 tile -> bf16 LDS, lane-major (conflict-free, coalesced)
  #pragma unroll
  for (int e=0;e<8;e++){
    int idx = e*64 + lane;          // 0..511 float4s
    int r = idx >> 5, j4 = idx & 31;
    long srow;
    if (gather0){
      int a = adj[node*16 + r];
      srow = (long)(((b<<10) + a))*128;
    } else {
      srow = (long)(node*16 + r)*128;
    }
    float4 v = *reinterpret_cast<const float4*>(&hsrc[srow + j4*4]);
    short4 s; s.x=f2bf(v.x); s.y=f2bf(v.y); s.z=f2bf(v.z); s.w=f2bf(v.w);
    *reinterpret_cast<short4*>(&As[w][r][j4*4]) = s;
  }
  __syncthreads();
  int l15 = lane & 15, quad = lane >> 4;
  f32x4 acc[8];
  #pragma unroll
  for (int u=0;u<8;u++) acc[u] = (f32x4){0.f,0.f,0.f,0.f};
  #pragma unroll
  for (int kc=0; kc<4; kc++){
    int k0 = kc*32;
    bf16x8 a = *reinterpret_cast<const bf16x8*>(&As[w][l15][k0 + quad*8]);
    #pragma unroll
    for (int u=0;u<8;u++){
      bf16x8 bfr = *reinterpret_cast<const bf16x8*>(&Wgt[(16*u + l15)*128 + k0 + quad*8]);
      acc[u] = __builtin_amdgcn_mfma_f32_16x16x32_bf16(a, bfr, acc[u], 0,0,0);
    }
  }
  float tv[8][4];
  float lp[4] = {0.f,0.f,0.f,0.f};
  #pragma unroll
  for (int u=0;u<8;u++){
    int c = 16*u + l15;
    float bgc = bg[c], agc = ag[c];
    #pragma unroll
    for (int reg=0;reg<4;reg++){
      float t = ftanh(acc[u][reg] + bgc);
      tv[u][reg] = t;
      lp[reg] += t * agc;
    }
  }
  #pragma unroll
  for (int reg=0;reg<4;reg++){
    lp[reg] += __shfl_xor(lp[reg], 1);
    lp[reg] += __shfl_xor(lp[reg], 2);
    lp[reg] += __shfl_xor(lp[reg], 4);
    lp[reg] += __shfl_xor(lp[reg], 8);
  }
  float m4 = fmaxf(fmaxf(lp[0],lp[1]), fmaxf(lp[2],lp[3]));
  m4 = fmaxf(m4, __shfl_xor(m4, 16));
  m4 = fmaxf(m4, __shfl_xor(m4, 32));
  float e4[4]; float s4 = 0.f;
  #pragma unroll
  for (int reg=0;reg<4;reg++){ e4[reg] = __expf(lp[reg]-m4); s4 += e4[reg]; }
  s4 += __shfl_xor(s4, 16);
  s4 += __shfl_xor(s4, 32);
  float inv = frcp(s4);
  #pragma unroll
  for (int reg=0;reg<4;reg++) e4[reg] *= inv;
  #pragma unroll
  for (int u=0;u<8;u++){
    float mp = e4[0]*tv[u][0] + e4[1]*tv[u][1] + e4[2]*tv[u][2] + e4[3]*tv[u][3];
    mp += __shfl_xor(mp, 16);
    mp += __shfl_xor(mp, 32);
    if (quad == 0) nmsg[node*128 + 16*u + l15] = mp;
  }
}

// MFMA GRU: 64 edge-rows/block. layer0: old-h := gather(ne,adj) (same lines as x's ne read).
// Epilogue reads old-h from LDS (bf16) — no global re-read.
__global__ __launch_bounds__(256) void k_gru_mfma(const float* __restrict__ ne, const float* __restrict__ nmsg,
    const int* __restrict__ adj, const short* __restrict__ Wt, const float* __restrict__ bgru,
    float* __restrict__ h, int layer0){
  __shared__ short As[64][264];
  int tid = threadIdx.x;
  int ge0 = blockIdx.x*64;
  // x-half (and layer0 h-half): lane-major over 64 rows x 32 float4
  #pragma unroll
  for (int e=0;e<8;e++){
    int idx = e*256 + tid;          // 0..2047
    int r = idx >> 5, j4 = idx & 31;
    int ge = ge0 + r;
    int nv = ge >> 4, d = ge & 15;
    int a = adj[nv*16 + d];
    long srow = (long)(((nv >> 10)<<10) + a)*128;
    float4 m4 = *reinterpret_cast<const float4*>(&nmsg[srow + j4*4]);
    float4 e4 = *reinterpret_cast<const float4*>(&ne[srow + j4*4]);
    short4 s;
    s.x = f2bf(ftanh(m4.x+e4.x)); s.y = f2bf(ftanh(m4.y+e4.y));
    s.z = f2bf(ftanh(m4.z+e4.z)); s.w = f2bf(ftanh(m4.w+e4.w));
    *reinterpret_cast<short4*>(&As[r][j4*4]) = s;
    if (layer0){
      short4 sh; sh.x=f2bf(e4.x); sh.y=f2bf(e4.y); sh.z=f2bf(e4.z); sh.w=f2bf(e4.w);
      *reinterpret_cast<short4*>(&As[r][128 + j4*4]) = sh;
    }
  }
  if (!layer0){
    #pragma unroll
    for (int e=0;e<8;e++){
      int idx = e*256 + tid;
      int r = idx >> 5, j4 = idx & 31;
      float4 h4 = *reinterpret_cast<const float4*>(&h[(long)(ge0 + r)*128 + j4*4]);
      short4 s; s.x=f2bf(h4.x); s.y=f2bf(h4.y); s.z=f2bf(h4.z); s.w=f2bf(h4.w);
      *reinterpret_cast<short4*>(&As[r][128 + j4*4]) = s;
    }
  }
  __syncthreads();
  int w = tid >> 6, lane = tid & 63;
  int l15 = lane & 15, quad = lane >> 4;
  f32x4 acc[4][4][2];
  #pragma unroll
  for (int mt=0;mt<4;mt++)
    #pragma unroll
    for (int g=0;g<4;g++)
      #pragma unroll
      for (int u=0;u<2;u++) acc[mt][g][u] = (f32x4){0.f,0.f,0.f,0.f};

  for (int k8=0;k8<8;k8++){
    int k0 = k8*32;
    int gg = (k8 < 4) ? 2 : 3;
    bf16x8 a[4];
    #pragma unroll
    for (int mt=0;mt<4;mt++)
      a[mt] = *reinterpret_cast<const bf16x8*>(&As[16*mt + l15][k0 + quad*8]);
    bf16x8 bz[2], br[2], bc[2];
    #pragma unroll
    for (int u=0;u<2;u++){
      int ncol = 32*w + 16*u + l15;
      int koff = k0 + quad*8;
      bz[u] = *reinterpret_cast<const bf16x8*>(&Wt[(ncol      )*256 + koff]);
      br[u] = *reinterpret_cast<const bf16x8*>(&Wt[(ncol + 128)*256 + koff]);
      bc[u] = *reinterpret_cast<const bf16x8*>(&Wt[(ncol + gg*128)*256 + koff]);
    }
    #pragma unroll
    for (int mt=0;mt<4;mt++){
      #pragma unroll
      for (int u=0;u<2;u++){
        acc[mt][0][u]  = __builtin_amdgcn_mfma_f32_16x16x32_bf16(a[mt], bz[u], acc[mt][0][u], 0,0,0);
        acc[mt][1][u]  = __builtin_amdgcn_mfma_f32_16x16x32_bf16(a[mt], br[u], acc[mt][1][u], 0,0,0);
        acc[mt][gg][u] = __builtin_amdgcn_mfma_f32_16x16x32_bf16(a[mt], bc[u], acc[mt][gg][u], 0,0,0);
      }
    }
  }
  #pragma unroll
  for (int u=0;u<2;u++){
    int j = 32*w + 16*u + l15;
    float bjz = bgru[j], bjr = bgru[128 + j], bjc = bgru[256 + j];
    #pragma unroll
    for (int mt=0;mt<4;mt++){
      #pragma unroll
      for (int reg=0;reg<4;reg++){
        int rl = 16*mt + quad*4 + reg;
        float z = fsig(acc[mt][0][u][reg] + bjz);
        float r = fsig(acc[mt][1][u][reg] + bjr);
        float cand = ftanh(acc[mt][2][u][reg] + bjc + r*acc[mt][3][u][reg]);
        float ho = bf2f(As[rl][128 + j]);
        h[(long)(ge0 + rl)*128 + j] = z*ho + (1.f - z)*cand;
      }
    }
  }
}

// MFMA decoder: wave-per-16-edges. dec_in=[h | h+h_opp] @ W1t, tanh, *W2 reduce.
__global__ __launch_bounds__(256) void k_dec_mfma(const float* __restrict__ h, const int* __restrict__ adj,
    const short* __restrict__ W1t, const float* __restrict__ b1, const float* __restrict__ W2,
    const float* __restrict__ b2_, float* __restrict__ nw){
  __shared__ short Ds[4][16][264];
  int tid = threadIdx.x;
  int w = tid >> 6, lane = tid & 63;
  int ge0 = blockIdx.x*64 + w*16;
  #pragma unroll
  for (int e=0;e<8;e++){
    int idx = e*64 + lane;          // 0..511
    int r = idx >> 5, j4 = idx & 31;
    int ge = ge0 + r;
    int nv = ge >> 4, d = ge & 15, b = nv >> 10;
    int a = adj[nv*16 + d];
    long opp = ((long)(((b<<10) + a)*16 + (d^1)))*128;
    float4 ov = *reinterpret_cast<const float4*>(&h[(long)ge*128 + j4*4]);
    float4 pv = *reinterpret_cast<const float4*>(&h[opp + j4*4]);
    short4 s1; s1.x=f2bf(ov.x); s1.y=f2bf(ov.y); s1.z=f2bf(ov.z); s1.w=f2bf(ov.w);
    *reinterpret_cast<short4*>(&Ds[w][r][j4*4]) = s1;
    short4 s2; s2.x=f2bf(ov.x+pv.x); s2.y=f2bf(ov.y+pv.y); s2.z=f2bf(ov.z+pv.z); s2.w=f2bf(ov.w+pv.w);
    *reinterpret_cast<short4*>(&Ds[w][r][128 + j4*4]) = s2;
  }
  __syncthreads();
  int l15 = lane & 15, quad = lane >> 4;
  f32x4 acc[4];
  #pragma unroll
  for (int u=0;u<4;u++) acc[u] = (f32x4){0.f,0.f,0.f,0.f};
  #pragma unroll
  for (int kc=0;kc<8;kc++){
    int k0 = kc*32;
    bf16x8 av = *reinterpret_cast<const bf16x8*>(&Ds[w][l15][k0 + quad*8]);
    #pragma unroll
    for (int u=0;u<4;u++){
      bf16x8 bfr = *reinterpret_cast<const bf16x8*>(&W1t[(16*u + l15)*256 + k0 + quad*8]);
      acc[u] = __builtin_amdgcn_mfma_f32_16x16x32_bf16(av, bfr, acc[u], 0,0,0);
    }
  }
  float p[4] = {0.f,0.f,0.f,0.f};
  #pragma unroll
  for (int u=0;u<4;u++){
    int c = 16*u + l15;
    float bc = b1[c], wc = W2[c];
    #pragma unroll
    for (int reg=0;reg<4;reg++) p[reg] += ftanh(acc[u][reg] + bc) * wc;
  }
  #pragma unroll
  for (int reg=0;reg<4;reg++){
    p[reg] += __shfl_xor(p[reg], 1);
    p[reg] += __shfl_xor(p[reg], 2);
    p[reg] += __shfl_xor(p[reg], 4);
    p[reg] += __shfl_xor(p[reg], 8);
  }
  if (l15 == 0){
    float b2v = b2_[0];
    #pragma unroll
    for (int reg=0;reg<4;reg++) nw[ge0 + quad*4 + reg] = p[reg] + b2v;
  }
}

// dest_attn = softmax_d( nw[b, inv_adj[v,d], d] )
__global__ __launch_bounds__(256) void k_dattn(const float* __restrict__ nw, const int* __restrict__ invadj,
                                               float* __restrict__ dattn){
  int node = blockIdx.x*256 + threadIdx.x;
  if (node >= BV) return;
  int b = node >> 10;
  float vals[16];
  #pragma unroll
  for (int d=0; d<16; d++){
    int ia = invadj[node*D + d];
    vals[d] = nw[(b*V + ia)*D + d];
  }
  float m = vals[0];
  #pragma unroll
  for (int d=1; d<16; d++) m = fmaxf(m, vals[d]);
  float s = 0.f;
  #pragma unroll
  for (int d=0; d<16; d++){ vals[d] = __expf(vals[d]-m); s += vals[d]; }
  float inv = frcp(s);
  #pragma unroll
  for (int d=0; d<16; d++) dattn[node*D + d] = vals[d]*inv;
}

// normalized = sparsemax_d( dattn[b, adj[v,d], d] )
__global__ __launch_bounds__(256) void k_sparse(const float* __restrict__ dattn, const int* __restrict__ adj,
                                                float* __restrict__ norm_){
  int node = blockIdx.x*256 + threadIdx.x;
  if (node >= BV) return;
  int b = node >> 10;
  float z[16], s[16];
  #pragma unroll
  for (int d=0; d<16; d++){
    int a = adj[node*D + d];
    z[d] = dattn[(b*V + a)*D + d];
    s[d] = z[d];
  }
  #pragma unroll
  for (int k2 = 2; k2 <= 16; k2 <<= 1){
    #pragma unroll
    for (int jj = k2 >> 1; jj > 0; jj >>= 1){
      #pragma unroll
      for (int i = 0; i < 16; i++){
        int l = i ^ jj;
        if (l > i){
          bool up = ((i & k2) == 0);
          float a = s[i], bb = s[l];
          bool sw = up ? (a > bb) : (a < bb);
          if (sw){ s[i]=bb; s[l]=a; }
        }
      }
    }
  }
  float cs = 0.f, zcs = 0.f; int kz = 1;
  #pragma unroll
  for (int j=0;j<16;j++){
    float zj = s[15-j];
    cs += zj;
    if (1.f + (float)(j+1)*zj > cs){ kz = j+1; zcs = cs; }
  }
  float tau = (zcs - 1.f)/(float)kz;
  #pragma unroll
  for (int d=0; d<16; d++) norm_[node*D + d] = fmaxf(z[d]-tau, 0.f);
}

// all 10 MCF iterations fused: one block per batch, flow in LDS d-major.
__global__ __launch_bounds__(1024) void k_flow_fused(const float* __restrict__ norm_,
    const float* __restrict__ dem, const int* __restrict__ invadj, float* __restrict__ flowout){
  __shared__ float fl[D*V];
  int b = blockIdx.x, v = threadIdx.x;
  int base = ((b << 10) + v)*D;
  int ia[16]; float nr[16];
  #pragma unroll
  for (int d4=0; d4<4; d4++){
    int4 i4 = reinterpret_cast<const int4*>(&invadj[base])[d4];
    ia[d4*4+0]=i4.x; ia[d4*4+1]=i4.y; ia[d4*4+2]=i4.z; ia[d4*4+3]=i4.w;
    float4 n4 = reinterpret_cast<const float4*>(&norm_[base])[d4];
    nr[d4*4+0]=n4.x; nr[d4*4+1]=n4.y; nr[d4*4+2]=n4.z; nr[d4*4+3]=n4.w;
  }
  float dm = dem[(b<<10) + v];
  #pragma unroll
  for (int d=0; d<16; d++) fl[d*V + v] = 0.f;
  __syncthreads();
  float s = 0.f;
  for (int it=0; it<10; it++){
    float inflow = 0.f;
    #pragma unroll
    for (int d=0; d<16; d++) inflow += fl[d*V + ia[d]];
    __syncthreads();
    s = fmaxf(inflow - dm, 0.f);
    #pragma unroll
    for (int d=0; d<16; d++) fl[d*V + v] = nr[d]*s;
    __syncthreads();
  }
  #pragma unroll
  for (int d4=0; d4<4; d4++){
    float4 o;
    o.x = nr[d4*4+0]*s; o.y = nr[d4*4+1]*s; o.z = nr[d4*4+2]*s; o.w = nr[d4*4+3]*s;
    reinterpret_cast<float4*>(&flowout[base])[d4] = o;
  }
}

// dual_vars per node + dual_demand accumulation
__global__ __launch_bounds__(128) void k_dualvars(const float* __restrict__ h, const float* __restrict__ W1,
    const float* __restrict__ b1, const float* __restrict__ W2, const float* __restrict__ b2_,
    const float* __restrict__ dem, float* __restrict__ dv, float* __restrict__ accdd){
  __shared__ float ns[128];
  int node = blockIdx.x; int b = node >> 10;
  int tid = threadIdx.x;
  float s = 0.f;
  #pragma unroll
  for (int d=0; d<16; d++) s += h[(long)(node*D + d)*H + tid];
  ns[tid] = s;
  __syncthreads();
  if (tid < 64){
    float acc = 0.f;
    for (int k=0;k<128;k++) acc += ns[k]*W1[k*HD + tid];
    float t = ftanh(acc + b1[tid]) * W2[tid];
    #pragma unroll
    for (int off=32; off>0; off>>=1) t += __shfl_down(t, off);
    if (tid == 0){
      float val = fmaxf(t + b2_[0], 0.f);
      dv[node] = val;
      atomicAdd(&accdd[b], val * dem[node]);
    }
  }
}

// flow cost + dual flow iterations + dual cost
__global__ __launch_bounds__(256) void k_cost(const float* __restrict__ flow, const float* __restrict__ dv,
    const int* __restrict__ adj, float* __restrict__ accF, float* __restrict__ accD){
  int gid = blockIdx.x*256 + threadIdx.x;
  int b = gid >> 14;
  int a = adj[gid];
  float diff = dv[b*V + a];
  float f = 0.f, vel = 0.f;
  #pragma unroll
  for (int it=0; it<10; it++){
    float g = 2.f*f + diff;
    vel = 0.9f*vel - 0.01f*g;
    f = fmaxf(f + vel, 0.f);
  }
  float cd = f*f + diff*f;
  float fl = flow[gid];
  float cf = fl*fl;
  #pragma unroll
  for (int off=32; off>0; off>>=1){ cd += __shfl_down(cd, off); cf += __shfl_down(cf, off); }
  __shared__ float r1[4], r2[4];
  int lane = threadIdx.x & 63, w = threadIdx.x >> 6;
  if (lane==0){ r1[w]=cf; r2[w]=cd; }
  __syncthreads();
  if (threadIdx.x==0){
    atomicAdd(&accF[b], r1[0]+r1[1]+r1[2]+r1[3]);
    atomicAdd(&accD[b], r2[0]+r2[1]+r2[2]+r2[3]);
  }
}

__global__ __launch_bounds__(64) void k_final(const float* __restrict__ acc, float* __restrict__ out){
  int b = threadIdx.x;
  if (b < B){
    float fc = acc[b], dc = acc[16+b], dd = acc[32+b];
    out[b] = fc - (dc - dd);
  }
}

extern "C" void kernel_launch(void* const* d_in, const int* in_sizes, int n_in,
                              void* d_out, int out_size, void* d_ws, size_t ws_size,
                              hipStream_t stream){
  (void)in_sizes; (void)n_in; (void)out_size; (void)ws_size;
  const float* demands = (const float*)d_in[0];
  const float* nf      = (const float*)d_in[1];
  const float* emb     = (const float*)d_in[4];
  const float* Wenc    = (const float*)d_in[5];
  const float* benc    = (const float*)d_in[6];
  const float* Wgat    = (const float*)d_in[7];
  const float* bgat    = (const float*)d_in[8];
  const float* agat    = (const float*)d_in[9];
  const float* Wgx     = (const float*)d_in[10];
  const float* Wgh     = (const float*)d_in[11];
  const float* bgru    = (const float*)d_in[12];
  const float* Wd1     = (const float*)d_in[13];
  const float* bd1     = (const float*)d_in[14];
  const float* Wd2     = (const float*)d_in[15];
  const float* bd2     = (const float*)d_in[16];
  const float* Wu1     = (const float*)d_in[17];
  const float* bu1     = (const float*)d_in[18];
  const float* Wu2     = (const float*)d_in[19];
  const float* bu2     = (const float*)d_in[20];
  const int* adj       = (const int*)d_in[21];
  const int* invadj    = (const int*)d_in[22];

  float* ws    = (float*)d_ws;
  float* ne    = ws + OFF_NODE_ENC;
  float* h     = ws + OFF_H;
  float* nmsg  = ws + OFF_NMSG;
  float* embn  = ws + OFF_EMB;
  float* nw    = ws + OFF_NW;
  float* dattn = ws + OFF_DATTN;
  float* nrm   = ws + OFF_NORM;
  float* fa    = ws + OFF_FLOWA;
  float* dv    = ws + OFF_DV;
  float* acc   = ws + OFF_ACC;
  short* wt    = (short*)(ws + OFF_WT);
  short* wtg   = (short*)(ws + OFF_WTG);
  short* wtd   = (short*)(ws + OFF_WTD);

  k_prep<<<897, 256, 0, stream>>>(Wgx, Wgh, Wgat, Wd1, emb, wt, wtg, wtd, embn, acc);
  k_enc<<<BV/16, 256, 0, stream>>>(embn, nf, Wenc, benc, ne);
  // layer 0: h == gather(ne, adj) — read ne directly, no hinit
  k_gat_mfma<<<BV/4, 256, 0, stream>>>(ne, adj, wtg, bgat, agat, nmsg, 1);
  k_gru_mfma<<<BVD/64, 256, 0, stream>>>(ne, nmsg, adj, wt, bgru, h, 1);
  // layer 1
  k_gat_mfma<<<BV/4, 256, 0, stream>>>(h, adj, wtg, bgat, agat, nmsg, 0);
  k_gru_mfma<<<BVD/64, 256, 0, stream>>>(ne, nmsg, adj, wt, bgru, h, 0);
  k_dec_mfma<<<BVD/64, 256, 0, stream>>>(h, adj, wtd, bd1, Wd2, bd2, nw);
  k_dattn<<<BV/256, 256, 0, stream>>>(nw, invadj, dattn);
  k_sparse<<<BV/256, 256, 0, stream>>>(dattn, adj, nrm);
  k_flow_fused<<<B, 1024, 0, stream>>>(nrm, demands, invadj, fa);
  k_dualvars<<<BV, 128, 0, stream>>>(h, Wu1, bu1, Wu2, bu2, demands, dv, acc+32);
  k_cost<<<BVD/256, 256, 0, stream>>>(fa, dv, adj, acc, acc+16);
  k_final<<<1, 64, 0, stream>>>(acc, (float*)d_out);
}